// Round 11
// baseline (171.085 us; speedup 1.0000x reference)
//
#include <hip/hip_runtime.h>
#include <stdint.h>
#include <math.h>

// Problem constants
#define NPTS 32768
#define PP   5
#define MM   1024
#define JJ   24
#define HH   256

// out (f32 element offsets), total 2,293,760 floats
#define O0 0                // tpose        [1,N,P,3]
#define O1 491520           // tpose_dirs   [1,N,P,3]
#define O2 983040           // resd         [1,N,P,3]
#define O3 1474560          // pflag        [1,N,P]
#define O4 1638400          // init_bigpose [1,N*P,3]
#define O5 2129920          // pnorm        [1,N*P]

typedef unsigned short ushort_t;
typedef unsigned int   uint_t;
typedef unsigned long long u64_t;
typedef __attribute__((ext_vector_type(8))) short bf16x8;
typedef __attribute__((ext_vector_type(4))) float f32x4;
typedef __attribute__((ext_vector_type(2))) float f32x2;

__device__ __forceinline__ ushort_t f2bf(float f) {
  union { uint_t i; float f; } v; v.f = f;
  uint_t i = v.i;
  return (ushort_t)((i + 0x7FFFu + ((i >> 16) & 1u)) >> 16);  // RNE
}
// hardware packed f32->bf16 (RNE, bit-identical to f2bf for finite values)
__device__ __forceinline__ uint_t cvt_pk_bf16(float lo, float hi) {
  uint_t r;
  asm("v_cvt_pk_bf16_f32 %0, %1, %2" : "=v"(r) : "v"(lo), "v"(hi));
  return r;
}
__device__ __forceinline__ float tanh_fast(float v) {
  v = fminf(fmaxf(v, -15.f), 15.f);
  float e = __expf(2.f*v);               // v_exp_f32 path
  return __fdividef(e - 1.f, e + 1.f);   // abs err < 1e-6, plenty for tolerance
}
// 16-lane sum via DPP row_shl tree (VALU pipe). Result in lane m16==0.
__device__ __forceinline__ float dpp_sum16(float x) {
  x += __int_as_float(__builtin_amdgcn_update_dpp(0, __float_as_int(x), 0x108, 0xF, 0xF, true)); // row_shl:8
  x += __int_as_float(__builtin_amdgcn_update_dpp(0, __float_as_int(x), 0x104, 0xF, 0xF, true)); // row_shl:4
  x += __int_as_float(__builtin_amdgcn_update_dpp(0, __float_as_int(x), 0x102, 0xF, 0xF, true)); // row_shl:2
  x += __int_as_float(__builtin_amdgcn_update_dpp(0, __float_as_int(x), 0x101, 0xF, 0xF, true)); // row_shl:1
  return x;
}

// ---------------- prep: W2 f32 -> bf16 in MFMA B-fragment order ----------------
__global__ __launch_bounds__(256) void prep_w2(const float* __restrict__ W2g,
                                               ushort_t* __restrict__ W2bf)
{
  int k = blockIdx.x;
  int n = threadIdx.x;
  float v = W2g[k*256 + n];
  int kc = k >> 5, quad = (k & 31) >> 3, j = k & 7;
  int tile = n >> 4, lane = quad*16 + (n & 15);
  W2bf[kc*8192 + tile*512 + lane*8 + j] = f2bf(v);
}

// ---------------- LBS transform for one (n,p) row ----------------
__device__ __forceinline__ void transform_one(
    int n, int p, int nn, float pn, float fl,
    float px, float py, float pz, float dx, float dy, float dz,
    const float* __restrict__ pbw,
    const float4* __restrict__ sA4, const float4* __restrict__ sB4,
    float* __restrict__ out, float4* __restrict__ sib)
{
  const float4* bwr = (const float4*)(pbw + ((size_t)p * MM + nn) * JJ);
  float bw[24];
  #pragma unroll
  for (int q = 0; q < 6; ++q) {
    float4 u = bwr[q];
    bw[q*4+0] = u.x; bw[q*4+1] = u.y; bw[q*4+2] = u.z; bw[q*4+3] = u.w;
  }

  float M1[12], M2[12];
  #pragma unroll
  for (int q = 0; q < 12; ++q) { M1[q] = 0.f; M2[q] = 0.f; }
  #pragma unroll
  for (int j = 0; j < 24; ++j) {
    float w = bw[j];
    float4 a0 = sA4[j*3+0], a1 = sA4[j*3+1], a2 = sA4[j*3+2];
    M1[0]=fmaf(w,a0.x,M1[0]); M1[1]=fmaf(w,a0.y,M1[1]); M1[2]=fmaf(w,a0.z,M1[2]); M1[3]=fmaf(w,a0.w,M1[3]);
    M1[4]=fmaf(w,a1.x,M1[4]); M1[5]=fmaf(w,a1.y,M1[5]); M1[6]=fmaf(w,a1.z,M1[6]); M1[7]=fmaf(w,a1.w,M1[7]);
    M1[8]=fmaf(w,a2.x,M1[8]); M1[9]=fmaf(w,a2.y,M1[9]); M1[10]=fmaf(w,a2.z,M1[10]); M1[11]=fmaf(w,a2.w,M1[11]);
    float4 c0 = sB4[j*3+0], c1 = sB4[j*3+1], c2 = sB4[j*3+2];
    M2[0]=fmaf(w,c0.x,M2[0]); M2[1]=fmaf(w,c0.y,M2[1]); M2[2]=fmaf(w,c0.z,M2[2]); M2[3]=fmaf(w,c0.w,M2[3]);
    M2[4]=fmaf(w,c1.x,M2[4]); M2[5]=fmaf(w,c1.y,M2[5]); M2[6]=fmaf(w,c1.z,M2[6]); M2[7]=fmaf(w,c1.w,M2[7]);
    M2[8]=fmaf(w,c2.x,M2[8]); M2[9]=fmaf(w,c2.y,M2[9]); M2[10]=fmaf(w,c2.z,M2[10]); M2[11]=fmaf(w,c2.w,M2[11]);
  }
  float a=M1[0], b=M1[1], c=M1[2];
  float d=M1[4], e=M1[5], f=M1[6];
  float g=M1[8], h=M1[9], i=M1[10];
  float C00 = e*i - f*h, C01 = c*h - b*i, C02 = b*f - c*e;
  float C10 = f*g - d*i, C11 = a*i - c*g, C12 = c*d - a*f;
  float C20 = d*h - e*g, C21 = b*g - a*h, C22 = a*e - b*d;
  float det = a*C00 + b*C10 + c*C20;
  float rd = 1.0f / det;
  float tx = px - M1[3], ty = py - M1[7], tz = pz - M1[11];
  float t0 = rd * (C00*tx + C01*ty + C02*tz);
  float t1 = rd * (C10*tx + C11*ty + C12*tz);
  float t2 = rd * (C20*tx + C21*ty + C22*tz);
  float i0 = M2[0]*t0 + M2[1]*t1 + M2[2]*t2  + M2[3];
  float i1 = M2[4]*t0 + M2[5]*t1 + M2[6]*t2  + M2[7];
  float i2 = M2[8]*t0 + M2[9]*t1 + M2[10]*t2 + M2[11];
  float d0 = rd * (C00*dx + C01*dy + C02*dz);
  float d1 = rd * (C10*dx + C11*dy + C12*dz);
  float d2 = rd * (C20*dx + C21*dy + C22*dz);
  float e0 = M2[0]*d0 + M2[1]*d1 + M2[2]*d2;
  float e1 = M2[4]*d0 + M2[5]*d1 + M2[6]*d2;
  float e2 = M2[8]*d0 + M2[9]*d1 + M2[10]*d2;

  size_t k = (size_t)n * PP + p;   // n-major
  out[O1 + k*3+0] = e0; out[O1 + k*3+1] = e1; out[O1 + k*3+2] = e2;
  out[O3 + k] = fl;
  out[O4 + k*3+0] = i0; out[O4 + k*3+1] = i1; out[O4 + k*3+2] = i2;
  out[O5 + k] = pn;
  *sib = make_float4(i0, i1, i2, fl);   // pass-through to the fused MLP phase
}

// LDS overlay: phase-1 (nn scan) and phase-2 (mlp) reuse one region.
struct P1 {
  float4 sXq[256], sYq[256], sZq[256], sWq[256];  // 16KB SoA quads
  float4 sA4[72], sB4[72];                         // 2.3KB
};                                                 // 18688 B
struct P2 {
  ushort_t sH[4*8*512];   // 32KB: h1 A-frags [mt][kc][slot][8] (bank-XOR slots)
  float4 w1c[256];        // {W1[0][c], W1[1][c], W1[2][c], b1[c]}
  float4 w3b2[256];       // {W3[c][0], W3[c][1], W3[c][2], b2[c]}
  float  prt[64][4][3];   // per-row layer-3 partials per wave
};                                                 // 44032 B

// ---------------- fused nn + mlp: 1280 blocks x 256 threads ----------------
// Block b: p = b>>8, nb = b&255, rows n in [nb*128, nb*128+128).
// Phase 1 = round-6-verified nn scan + transform (59.3us standalone).
// Phase 2 = round-10-verified mlp body (coop h1 + column-split + DPP), run on
// the block's OWN 128 rows in 2 chunks of 64, reading init_bigpose/pflag from
// LDS (same bits transform_one wrote to out). No inter-block dependencies ->
// nn-VALU of some blocks overlaps mlp-MFMA/L2 of others on each CU.
__global__ __launch_bounds__(256) void fused_kernel(
    const float* __restrict__ pp0, const float* __restrict__ pp1,
    const float* __restrict__ part_pts, const float* __restrict__ pbw,
    const float* __restrict__ Ag, const float* __restrict__ Bg,
    const int* __restrict__ lengths2,
    const float* __restrict__ W1g, const float* __restrict__ b1g,
    const float* __restrict__ b2g, const float* __restrict__ W3g,
    const float* __restrict__ b3g, const ushort_t* __restrict__ W2bf,
    float* __restrict__ out)
{
  __shared__ __align__(16) char smem_raw[sizeof(P2)];  // 44032 B (>= sizeof(P1))
  __shared__ float4 sIB[128];                          // {i0,i1,i2,fl} per row
  P1& p1 = *reinterpret_cast<P1*>(smem_raw);
  P2& p2 = *reinterpret_cast<P2*>(smem_raw);

  int t = threadIdx.x;
  int p  = blockIdx.x >> 8;        // 256 blocks per part
  int nb = blockIdx.x & 255;
  int g  = t >> 3;                 // n-group 0..31
  int s  = t & 7;                  // m-slice 0..7
  int n0 = nb*128 + g*4;           // this lane's 4 points: n0..n0+3

  // pose-pair disambiguation (wave-uniform); pose_dirs rows unit-norm
  float s0r0 = pp0[0], s0r1 = pp0[1], s0r2 = pp0[2];
  float nrm = s0r0*s0r0 + s0r1*s0r1 + s0r2*s0r2;
  bool c0_is_dirs = fabsf(nrm - 1.0f) < 1e-4f;
  const float* pose_pts  = c0_is_dirs ? pp1 : pp0;
  const float* pose_dirs = c0_is_dirs ? pp0 : pp1;

  {
    #pragma clang fp contract(off)
    float* fX = (float*)p1.sXq; float* fY = (float*)p1.sYq;
    float* fZ = (float*)p1.sZq; float* fW = (float*)p1.sWq;
    for (int i = t; i < MM; i += 256) {
      float x = part_pts[((size_t)p*MM+i)*3+0];
      float y = part_pts[((size_t)p*MM+i)*3+1];
      float z = part_pts[((size_t)p*MM+i)*3+2];
      float yy = ((x*x) + (y*y)) + (z*z);
      fX[i] = x; fY[i] = y; fZ[i] = z; fW[i] = yy;
    }
  }
  for (int i = t; i < 72; i += 256) {
    int l = i*4;
    int j = l / 12, rc = l % 12;
    float4 qa, qb;
    qa.x = Ag[j*16+rc+0]; qa.y = Ag[j*16+rc+1]; qa.z = Ag[j*16+rc+2]; qa.w = Ag[j*16+rc+3];
    qb.x = Bg[j*16+rc+0]; qb.y = Bg[j*16+rc+1]; qb.z = Bg[j*16+rc+2]; qb.w = Bg[j*16+rc+3];
    p1.sA4[i] = qa; p1.sB4[i] = qb;
  }
  int mlen = lengths2[p]; if (mlen > MM) mlen = MM;
  __syncthreads();

  // load 4 points' coordinates (n0 % 4 == 0 -> 16B aligned); build doubled splats
  float X[4], Y[4], Z[4];
  f32x2 Xd[4], Yd[4], Zd[4], C2[4];
  {
    #pragma clang fp contract(off)
    const float4* pr = (const float4*)(pose_pts + (size_t)n0*3);
    float4 f0 = pr[0], f1 = pr[1], f2 = pr[2];
    X[0]=f0.x; Y[0]=f0.y; Z[0]=f0.z;
    X[1]=f0.w; Y[1]=f1.x; Z[1]=f1.y;
    X[2]=f1.z; Y[2]=f1.w; Z[2]=f2.x;
    X[3]=f2.y; Y[3]=f2.z; Z[3]=f2.w;
    #pragma unroll
    for (int j = 0; j < 4; ++j) {
      float x2 = ((X[j]*X[j]) + (Y[j]*Y[j])) + (Z[j]*Z[j]);
      Xd[j] = (f32x2){2.0f*X[j], 2.0f*X[j]};
      Yd[j] = (f32x2){2.0f*Y[j], 2.0f*Y[j]};
      Zd[j] = (f32x2){2.0f*Z[j], 2.0f*Z[j]};
      C2[j] = (f32x2){x2, x2};
    }
  }

  float best[4] = {INFINITY, INFINITY, INFINITY, INFINITY};
  int   code[4] = {0, 0, 0, 0};   // best m == ((code>>2)<<5) + 4*s + (code&3)
  {
    #pragma clang fp contract(off)
    int nq = mlen >> 5;                // full 32-blocks
    for (int k = 0; k < nq; ++k) {
      int qi = k*8 + s;                // quad index (8-way same-addr broadcast)
      float4 QX = p1.sXq[qi], QY = p1.sYq[qi], QZ = p1.sZq[qi], QW = p1.sWq[qi];
      f32x2 qx0 = {QX.x, QX.y}, qx1 = {QX.z, QX.w};
      f32x2 qy0 = {QY.x, QY.y}, qy1 = {QY.z, QY.w};
      f32x2 qz0 = {QZ.x, QZ.y}, qz1 = {QZ.z, QZ.w};
      f32x2 qw0 = {QW.x, QW.y}, qw1 = {QW.z, QW.w};
      int cb = k << 2;                 // lane-uniform (SGPR)
      #pragma unroll
      for (int j = 0; j < 4; ++j) {
        f32x2 dt0 = ((Xd[j]*qx0) + (Yd[j]*qy0)) + (Zd[j]*qz0);
        f32x2 tt0 = (C2[j] - dt0) + qw0;
        f32x2 dt1 = ((Xd[j]*qx1) + (Yd[j]*qy1)) + (Zd[j]*qz1);
        f32x2 tt1 = (C2[j] - dt1) + qw1;
        float e0 = fmaxf(tt0.x, 0.f);
        float e1 = fmaxf(tt0.y, 0.f);
        float e2 = fmaxf(tt1.x, 0.f);
        float e3 = fmaxf(tt1.y, 0.f);
        bool l0 = e0 < best[j]; best[j] = fminf(best[j], e0); code[j] = l0 ? cb       : code[j];
        bool l1 = e1 < best[j]; best[j] = fminf(best[j], e1); code[j] = l1 ? (cb | 1) : code[j];
        bool l2 = e2 < best[j]; best[j] = fminf(best[j], e2); code[j] = l2 ? (cb | 2) : code[j];
        bool l3 = e3 < best[j]; best[j] = fminf(best[j], e3); code[j] = l3 ? (cb | 3) : code[j];
      }
    }
    // tail: partial 32-block (not taken when mlen % 32 == 0)
    int mb0 = nq << 5;
    if (mb0 < mlen) {
      const float* fX = (const float*)p1.sXq; const float* fY = (const float*)p1.sYq;
      const float* fZ = (const float*)p1.sZq; const float* fW = (const float*)p1.sWq;
      #pragma unroll
      for (int e = 0; e < 4; ++e) {
        int m = mb0 + 4*s + e;
        if (m < mlen) {
          float qx = fX[m], qy = fY[m], qz = fZ[m], qw = fW[m];
          int cc = (nq << 2) | e;
          #pragma unroll
          for (int j = 0; j < 4; ++j) {
            float dt2 = ((Xd[j].x*qx) + (Yd[j].x*qy)) + (Zd[j].x*qz);
            float dd = fmaxf((C2[j].x - dt2) + qw, 0.0f);
            bool lt = dd < best[j];
            best[j] = fminf(best[j], dd);
            code[j] = lt ? cc : code[j];
          }
        }
      }
    }
  }

  // merge the 8 slices (butterfly within each 8-lane group), lexicographic
  u64_t pk[4];
  #pragma unroll
  for (int j = 0; j < 4; ++j) {
    int mj = ((code[j] >> 2) << 5) + 4*s + (code[j] & 3);
    pk[j] = ((u64_t)__float_as_uint(best[j]) << 32) | (uint_t)mj;
    u64_t o;
    o = __shfl_xor(pk[j], 1); if (o < pk[j]) pk[j] = o;
    o = __shfl_xor(pk[j], 2); if (o < pk[j]) pk[j] = o;
    o = __shfl_xor(pk[j], 4); if (o < pk[j]) pk[j] = o;
  }

  // lanes s=0..3 each transform one point; result also stashed in sIB
  if (s < 4) {
    u64_t mypk = (s==0) ? pk[0] : (s==1) ? pk[1] : (s==2) ? pk[2] : pk[3];
    float xa = (s==0) ? X[0] : (s==1) ? X[1] : (s==2) ? X[2] : X[3];
    float ya = (s==0) ? Y[0] : (s==1) ? Y[1] : (s==2) ? Y[2] : Y[3];
    float za = (s==0) ? Z[0] : (s==1) ? Z[1] : (s==2) ? Z[2] : Z[3];
    int n = n0 + s;
    int bm = (int)(mypk & 0xFFFFFFFFull);
    float bd = __uint_as_float((uint_t)(mypk >> 32));
    float pn = sqrtf(bd);
    float fl = ((double)pn < 0.08) ? 1.0f : 0.0f;
    float dxa = pose_dirs[n*3+0], dya = pose_dirs[n*3+1], dza = pose_dirs[n*3+2];
    transform_one(n, p, bm, pn, fl, xa, ya, za, dxa, dya, dza, pbw,
                  p1.sA4, p1.sB4, out, &sIB[g*4 + s]);
  }
  __syncthreads();   // phase 1 fully done (incl. transform reads of sA4/sB4)

  // ---------------- phase 2: MLP on this block's 128 rows ----------------
  int wave = t >> 6, lane = t & 63, quad = lane >> 4, m16 = lane & 15;
  {
    int c = t;   // 256 threads exactly (w1c/w3b2 don't overlap P1's region tail? they do - after sync, safe)
    p2.w1c[c]  = make_float4(W1g[c], W1g[256+c], W1g[512+c], b1g[c]);
    p2.w3b2[c] = make_float4(W3g[c*3+0], W3g[c*3+1], W3g[c*3+2], b2g[c]);
  }
  __syncthreads();   // params visible before sH build reads w1c

  #pragma unroll 1
  for (int ch = 0; ch < 2; ++ch) {
    // build h1 fragments once (coop): thread t -> col-octet (kcw,qd), rows rg*8..+7
    {
      int q8 = t & 31, rg = t >> 5;
      int kcw = q8 >> 2, qd = q8 & 3;
      int c0 = kcw*32 + qd*8;
      float4 wv[8];
      #pragma unroll
      for (int j = 0; j < 8; ++j) wv[j] = p2.w1c[c0 + j];
      #pragma unroll
      for (int rr = 0; rr < 8; ++rr) {
        int r = rg*8 + rr;
        float4 xyz = sIB[ch*64 + r];
        uint_t u0, u1, u2, u3;
        {
          float4 wA = wv[0], wB = wv[1];
          float hA = fmaxf(fmaf(xyz.z, wA.z, fmaf(xyz.y, wA.y, fmaf(xyz.x, wA.x, wA.w))), 0.f);
          float hB = fmaxf(fmaf(xyz.z, wB.z, fmaf(xyz.y, wB.y, fmaf(xyz.x, wB.x, wB.w))), 0.f);
          u0 = cvt_pk_bf16(hA, hB);
        }
        {
          float4 wA = wv[2], wB = wv[3];
          float hA = fmaxf(fmaf(xyz.z, wA.z, fmaf(xyz.y, wA.y, fmaf(xyz.x, wA.x, wA.w))), 0.f);
          float hB = fmaxf(fmaf(xyz.z, wB.z, fmaf(xyz.y, wB.y, fmaf(xyz.x, wB.x, wB.w))), 0.f);
          u1 = cvt_pk_bf16(hA, hB);
        }
        {
          float4 wA = wv[4], wB = wv[5];
          float hA = fmaxf(fmaf(xyz.z, wA.z, fmaf(xyz.y, wA.y, fmaf(xyz.x, wA.x, wA.w))), 0.f);
          float hB = fmaxf(fmaf(xyz.z, wB.z, fmaf(xyz.y, wB.y, fmaf(xyz.x, wB.x, wB.w))), 0.f);
          u2 = cvt_pk_bf16(hA, hB);
        }
        {
          float4 wA = wv[6], wB = wv[7];
          float hA = fmaxf(fmaf(xyz.z, wA.z, fmaf(xyz.y, wA.y, fmaf(xyz.x, wA.x, wA.w))), 0.f);
          float hB = fmaxf(fmaf(xyz.z, wB.z, fmaf(xyz.y, wB.y, fmaf(xyz.x, wB.x, wB.w))), 0.f);
          u3 = cvt_pk_bf16(hA, hB);
        }
        // bank-XOR slot: store row r15 at slot r15^kcw (reader uses m16^kc)
        int mt = r >> 4, r15 = r & 15;
        int l = qd*16 + (r15 ^ kcw);
        *(uint4*)(&p2.sH[((mt*8 + kcw)*64 + l)*8]) = make_uint4(u0, u1, u2, u3);
      }
    }
    __syncthreads();

    // K-loop: wave owns cols nt in [wave*4, wave*4+4)
    const ushort_t* Wlane = W2bf + (size_t)wave*2048 + lane*8;
    bf16x8 Bcur[4], Bnxt[4];
    #pragma unroll
    for (int q = 0; q < 4; ++q) Bcur[q] = *(const bf16x8*)(Wlane + q*512);  // kc=0

    f32x4 acc[16];                   // acc[mt*4+q]
    #pragma unroll
    for (int i = 0; i < 16; ++i) acc[i] = (f32x4){0.f,0.f,0.f,0.f};

    #pragma unroll 1
    for (int kc = 0; kc < 8; ++kc) {
      bf16x8 Af[4];
      int lslot = quad*16 + (m16 ^ kc);     // bank-XOR read slot
      #pragma unroll
      for (int mt = 0; mt < 4; ++mt)
        Af[mt] = *(const bf16x8*)(&p2.sH[((mt*8 + kc)*64 + lslot)*8]);
      if (kc < 7) {                  // prefetch next kc's B under this kc's MFMAs
        #pragma unroll
        for (int q = 0; q < 4; ++q)
          Bnxt[q] = *(const bf16x8*)(Wlane + (kc+1)*8192 + q*512);
      }
      #pragma unroll
      for (int mt = 0; mt < 4; ++mt)
        #pragma unroll
        for (int q = 0; q < 4; ++q)
          acc[mt*4+q] = __builtin_amdgcn_mfma_f32_16x16x32_bf16(Af[mt], Bcur[q], acc[mt*4+q], 0, 0, 0);
      if (kc < 7) {
        #pragma unroll
        for (int q = 0; q < 4; ++q) Bcur[q] = Bnxt[q];
      }
    }

    // epilogue: h2[row=mt*16+quad*4+reg][col=(wave*4+q)*16+m16] = acc[mt*4+q][reg]
    float4 cvq[4];
    #pragma unroll
    for (int q = 0; q < 4; ++q) cvq[q] = p2.w3b2[(wave*4+q)*16 + m16];

    #pragma unroll
    for (int mt = 0; mt < 4; ++mt) {
      #pragma unroll
      for (int reg = 0; reg < 4; ++reg) {
        float q0 = 0.f, q1 = 0.f, q2 = 0.f;
        #pragma unroll
        for (int q = 0; q < 4; ++q) {
          float h2 = fmaxf(acc[mt*4+q][reg] + cvq[q].w, 0.f);
          q0 = fmaf(h2, cvq[q].x, q0);
          q1 = fmaf(h2, cvq[q].y, q1);
          q2 = fmaf(h2, cvq[q].z, q2);
        }
        q0 = dpp_sum16(q0);
        q1 = dpp_sum16(q1);
        q2 = dpp_sum16(q2);
        if (m16 == 0) {
          int lr = mt*16 + quad*4 + reg;           // local row 0..63
          p2.prt[lr][wave][0] = q0;
          p2.prt[lr][wave][1] = q1;
          p2.prt[lr][wave][2] = q2;
        }
      }
    }
    __syncthreads();

    // combine: thread t -> (row = t>>2, comp = t&3), comp<3 active
    {
      int lr = t >> 2, c = t & 3;
      if (c < 3) {
        float v = ((p2.prt[lr][0][c] + p2.prt[lr][1][c]) + p2.prt[lr][2][c]) + p2.prt[lr][3][c];
        int n = nb*128 + ch*64 + lr;
        size_t k = (size_t)n * PP + p;
        float4 ib = sIB[ch*64 + lr];
        float iv = (c == 0) ? ib.x : (c == 1) ? ib.y : ib.z;
        float rr = 0.05f * tanh_fast(v + b3g[c]) * ib.w;
        out[O0 + k*3 + c] = iv + rr;
        out[O2 + k*3 + c] = rr;
      }
    }
    __syncthreads();   // chunk-1 sH build must not race chunk-0 prt reads
  }
}

extern "C" void kernel_launch(void* const* d_in, const int* in_sizes, int n_in,
                              void* d_out, int out_size, void* d_ws, size_t ws_size,
                              hipStream_t stream) {
  (void)out_size; (void)ws_size;
  // size-based slot remap (no-op under documented dict order; protective otherwise)
  const int want[13] = {98304, 98304, 15360, 122880, 384, 384, 768, 256, 65536, 256, 768, 3, 5};
  int idx[13];
  bool used[64] = {false};
  for (int L = 0; L < 13; ++L) {
    idx[L] = -1;
    for (int s = 0; s < n_in && s < 64; ++s) {
      if (!used[s] && in_sizes[s] == want[L]) { idx[L] = s; used[s] = true; break; }
    }
    if (idx[L] < 0) idx[L] = L;
  }
  const float* pp0       = (const float*)d_in[idx[0]];
  const float* pp1       = (const float*)d_in[idx[1]];
  const float* part_pts  = (const float*)d_in[idx[2]];
  const float* part_pbw  = (const float*)d_in[idx[3]];
  const float* A         = (const float*)d_in[idx[4]];
  const float* bigA      = (const float*)d_in[idx[5]];
  const float* W1        = (const float*)d_in[idx[6]];
  const float* b1        = (const float*)d_in[idx[7]];
  const float* W2        = (const float*)d_in[idx[8]];
  const float* b2        = (const float*)d_in[idx[9]];
  const float* W3        = (const float*)d_in[idx[10]];
  const float* b3        = (const float*)d_in[idx[11]];
  const int*   lengths2  = (const int*)d_in[idx[12]];
  float* out = (float*)d_out;
  ushort_t* W2bf = (ushort_t*)d_ws;   // 128 KB of workspace

  prep_w2<<<256, 256, 0, stream>>>(W2, W2bf);
  fused_kernel<<<1280, 256, 0, stream>>>(pp0, pp1, part_pts, part_pbw,
                                         A, bigA, lengths2,
                                         W1, b1, b2, W3, b3, W2bf, out);
}

// Round 12
// 171.056 us; speedup vs baseline: 1.0002x; 1.0002x over previous
//
#include <hip/hip_runtime.h>
#include <stdint.h>
#include <math.h>

// Problem constants
#define NPTS 32768
#define PP   5
#define MM   1024
#define JJ   24
#define HH   256

// out (f32 element offsets), total 2,293,760 floats
#define O0 0                // tpose        [1,N,P,3]
#define O1 491520           // tpose_dirs   [1,N,P,3]
#define O2 983040           // resd         [1,N,P,3]
#define O3 1474560          // pflag        [1,N,P]
#define O4 1638400          // init_bigpose [1,N*P,3]
#define O5 2129920          // pnorm        [1,N*P]

typedef unsigned short ushort_t;
typedef unsigned int   uint_t;
typedef unsigned long long u64_t;
typedef __attribute__((ext_vector_type(8))) short bf16x8;
typedef __attribute__((ext_vector_type(4))) float f32x4;
typedef __attribute__((ext_vector_type(2))) float f32x2;

__device__ __forceinline__ ushort_t f2bf(float f) {
  union { uint_t i; float f; } v; v.f = f;
  uint_t i = v.i;
  return (ushort_t)((i + 0x7FFFu + ((i >> 16) & 1u)) >> 16);  // RNE
}
// hardware packed f32->bf16 (RNE, bit-identical to f2bf for finite values)
__device__ __forceinline__ uint_t cvt_pk_bf16(float lo, float hi) {
  uint_t r;
  asm("v_cvt_pk_bf16_f32 %0, %1, %2" : "=v"(r) : "v"(lo), "v"(hi));
  return r;
}
__device__ __forceinline__ float tanh_fast(float v) {
  v = fminf(fmaxf(v, -15.f), 15.f);
  float e = __expf(2.f*v);               // v_exp_f32 path
  return __fdividef(e - 1.f, e + 1.f);   // abs err < 1e-6, plenty for tolerance
}
// 16-lane sum via DPP row_shl tree (VALU pipe). Result in lane m16==0.
__device__ __forceinline__ float dpp_sum16(float x) {
  x += __int_as_float(__builtin_amdgcn_update_dpp(0, __float_as_int(x), 0x108, 0xF, 0xF, true)); // row_shl:8
  x += __int_as_float(__builtin_amdgcn_update_dpp(0, __float_as_int(x), 0x104, 0xF, 0xF, true)); // row_shl:4
  x += __int_as_float(__builtin_amdgcn_update_dpp(0, __float_as_int(x), 0x102, 0xF, 0xF, true)); // row_shl:2
  x += __int_as_float(__builtin_amdgcn_update_dpp(0, __float_as_int(x), 0x101, 0xF, 0xF, true)); // row_shl:1
  return x;
}

// ---------------- LBS transform for one (n,p) row ----------------
__device__ __forceinline__ void transform_one(
    int n, int p, int nn, float pn, float fl,
    float px, float py, float pz, float dx, float dy, float dz,
    const float* __restrict__ pbw,
    const float4* __restrict__ sA4, const float4* __restrict__ sB4,
    float* __restrict__ out)
{
  const float4* bwr = (const float4*)(pbw + ((size_t)p * MM + nn) * JJ);
  float bw[24];
  #pragma unroll
  for (int q = 0; q < 6; ++q) {
    float4 u = bwr[q];
    bw[q*4+0] = u.x; bw[q*4+1] = u.y; bw[q*4+2] = u.z; bw[q*4+3] = u.w;
  }

  float M1[12], M2[12];
  #pragma unroll
  for (int q = 0; q < 12; ++q) { M1[q] = 0.f; M2[q] = 0.f; }
  #pragma unroll
  for (int j = 0; j < 24; ++j) {
    float w = bw[j];
    float4 a0 = sA4[j*3+0], a1 = sA4[j*3+1], a2 = sA4[j*3+2];
    M1[0]=fmaf(w,a0.x,M1[0]); M1[1]=fmaf(w,a0.y,M1[1]); M1[2]=fmaf(w,a0.z,M1[2]); M1[3]=fmaf(w,a0.w,M1[3]);
    M1[4]=fmaf(w,a1.x,M1[4]); M1[5]=fmaf(w,a1.y,M1[5]); M1[6]=fmaf(w,a1.z,M1[6]); M1[7]=fmaf(w,a1.w,M1[7]);
    M1[8]=fmaf(w,a2.x,M1[8]); M1[9]=fmaf(w,a2.y,M1[9]); M1[10]=fmaf(w,a2.z,M1[10]); M1[11]=fmaf(w,a2.w,M1[11]);
    float4 c0 = sB4[j*3+0], c1 = sB4[j*3+1], c2 = sB4[j*3+2];
    M2[0]=fmaf(w,c0.x,M2[0]); M2[1]=fmaf(w,c0.y,M2[1]); M2[2]=fmaf(w,c0.z,M2[2]); M2[3]=fmaf(w,c0.w,M2[3]);
    M2[4]=fmaf(w,c1.x,M2[4]); M2[5]=fmaf(w,c1.y,M2[5]); M2[6]=fmaf(w,c1.z,M2[6]); M2[7]=fmaf(w,c1.w,M2[7]);
    M2[8]=fmaf(w,c2.x,M2[8]); M2[9]=fmaf(w,c2.y,M2[9]); M2[10]=fmaf(w,c2.z,M2[10]); M2[11]=fmaf(w,c2.w,M2[11]);
  }
  float a=M1[0], b=M1[1], c=M1[2];
  float d=M1[4], e=M1[5], f=M1[6];
  float g=M1[8], h=M1[9], i=M1[10];
  float C00 = e*i - f*h, C01 = c*h - b*i, C02 = b*f - c*e;
  float C10 = f*g - d*i, C11 = a*i - c*g, C12 = c*d - a*f;
  float C20 = d*h - e*g, C21 = b*g - a*h, C22 = a*e - b*d;
  float det = a*C00 + b*C10 + c*C20;
  float rd = 1.0f / det;
  float tx = px - M1[3], ty = py - M1[7], tz = pz - M1[11];
  float t0 = rd * (C00*tx + C01*ty + C02*tz);
  float t1 = rd * (C10*tx + C11*ty + C12*tz);
  float t2 = rd * (C20*tx + C21*ty + C22*tz);
  float i0 = M2[0]*t0 + M2[1]*t1 + M2[2]*t2  + M2[3];
  float i1 = M2[4]*t0 + M2[5]*t1 + M2[6]*t2  + M2[7];
  float i2 = M2[8]*t0 + M2[9]*t1 + M2[10]*t2 + M2[11];
  float d0 = rd * (C00*dx + C01*dy + C02*dz);
  float d1 = rd * (C10*dx + C11*dy + C12*dz);
  float d2 = rd * (C20*dx + C21*dy + C22*dz);
  float e0 = M2[0]*d0 + M2[1]*d1 + M2[2]*d2;
  float e1 = M2[4]*d0 + M2[5]*d1 + M2[6]*d2;
  float e2 = M2[8]*d0 + M2[9]*d1 + M2[10]*d2;

  size_t k = (size_t)n * PP + p;   // n-major
  out[O1 + k*3+0] = e0; out[O1 + k*3+1] = e1; out[O1 + k*3+2] = e2;
  out[O3 + k] = fl;
  out[O4 + k*3+0] = i0; out[O4 + k*3+1] = i1; out[O4 + k*3+2] = i2;
  out[O5 + k] = pn;
}

// grid: 1536 blocks x 256 threads. Blocks >=1280 do the W2->bf16 prep.
// Blocks <1280: p = b>>8, 128 n's (round-6-verified math) + software-pipelined
// quad loads: iteration k issues k+1's 4 ds_read_b128 BEFORE k's ~56-op
// compute body, so lgkmcnt waits are covered by a full iteration of VALU
// (round-11 counters: VALUBusy 70%, ~28% idle on LDS dependency).
__global__ __launch_bounds__(256) void nn_kernel(
    const float* __restrict__ pp0, const float* __restrict__ pp1,
    const float* __restrict__ part_pts, const float* __restrict__ pbw,
    const float* __restrict__ Ag, const float* __restrict__ Bg,
    const int* __restrict__ lengths2,
    const float* __restrict__ W2g, ushort_t* __restrict__ W2bf,
    float* __restrict__ out)
{
  // folded W2 prep (former prep_w2): blocks 1280..1535, k = bid-1280
  if (blockIdx.x >= 1280) {
    int k = blockIdx.x - 1280;
    int n = threadIdx.x;
    float v = W2g[k*256 + n];
    int kc = k >> 5, quad = (k & 31) >> 3, j = k & 7;
    int tile = n >> 4, lane = quad*16 + (n & 15);
    W2bf[kc*8192 + tile*512 + lane*8 + j] = f2bf(v);
    return;
  }

  __shared__ float4 sXq[256], sYq[256], sZq[256], sWq[256];  // SoA quads
  __shared__ float4 sA4[72];
  __shared__ float4 sB4[72];
  int t = threadIdx.x;
  int p  = blockIdx.x >> 8;        // 256 blocks per part
  int nb = blockIdx.x & 255;
  int g  = t >> 3;                 // n-group 0..31
  int s  = t & 7;                  // m-slice 0..7
  int n0 = nb*128 + g*4;           // this lane's 4 points: n0..n0+3

  // pose-pair disambiguation (wave-uniform); pose_dirs rows unit-norm
  float s0r0 = pp0[0], s0r1 = pp0[1], s0r2 = pp0[2];
  float nrm = s0r0*s0r0 + s0r1*s0r1 + s0r2*s0r2;
  bool c0_is_dirs = fabsf(nrm - 1.0f) < 1e-4f;
  const float* pose_pts  = c0_is_dirs ? pp1 : pp0;
  const float* pose_dirs = c0_is_dirs ? pp0 : pp1;

  {
    #pragma clang fp contract(off)
    float* fX = (float*)sXq; float* fY = (float*)sYq;
    float* fZ = (float*)sZq; float* fW = (float*)sWq;
    for (int i = t; i < MM; i += 256) {
      float x = part_pts[((size_t)p*MM+i)*3+0];
      float y = part_pts[((size_t)p*MM+i)*3+1];
      float z = part_pts[((size_t)p*MM+i)*3+2];
      float yy = ((x*x) + (y*y)) + (z*z);
      fX[i] = x; fY[i] = y; fZ[i] = z; fW[i] = yy;
    }
  }
  for (int i = t; i < 72; i += 256) {
    int l = i*4;
    int j = l / 12, rc = l % 12;
    float4 qa, qb;
    qa.x = Ag[j*16+rc+0]; qa.y = Ag[j*16+rc+1]; qa.z = Ag[j*16+rc+2]; qa.w = Ag[j*16+rc+3];
    qb.x = Bg[j*16+rc+0]; qb.y = Bg[j*16+rc+1]; qb.z = Bg[j*16+rc+2]; qb.w = Bg[j*16+rc+3];
    sA4[i] = qa; sB4[i] = qb;
  }
  int mlen = lengths2[p]; if (mlen > MM) mlen = MM;
  __syncthreads();

  // load 4 points' coordinates (n0 % 4 == 0 -> 16B aligned); build doubled splats
  float X[4], Y[4], Z[4];
  f32x2 Xd[4], Yd[4], Zd[4], C2[4];
  {
    #pragma clang fp contract(off)
    const float4* pr = (const float4*)(pose_pts + (size_t)n0*3);
    float4 f0 = pr[0], f1 = pr[1], f2 = pr[2];
    X[0]=f0.x; Y[0]=f0.y; Z[0]=f0.z;
    X[1]=f0.w; Y[1]=f1.x; Z[1]=f1.y;
    X[2]=f1.z; Y[2]=f1.w; Z[2]=f2.x;
    X[3]=f2.y; Y[3]=f2.z; Z[3]=f2.w;
    #pragma unroll
    for (int j = 0; j < 4; ++j) {
      float x2 = ((X[j]*X[j]) + (Y[j]*Y[j])) + (Z[j]*Z[j]);
      Xd[j] = (f32x2){2.0f*X[j], 2.0f*X[j]};
      Yd[j] = (f32x2){2.0f*Y[j], 2.0f*Y[j]};
      Zd[j] = (f32x2){2.0f*Z[j], 2.0f*Z[j]};
      C2[j] = (f32x2){x2, x2};
    }
  }

  float best[4] = {INFINITY, INFINITY, INFINITY, INFINITY};
  int   code[4] = {0, 0, 0, 0};   // best m == ((code>>2)<<5) + 4*s + (code&3)
  {
    #pragma clang fp contract(off)
    int nq = mlen >> 5;                // full 32-blocks
    if (nq > 0) {
      float4 QX = sXq[s], QY = sYq[s], QZ = sZq[s], QW = sWq[s];  // k=0
      for (int k = 0; k < nq; ++k) {
        // prefetch k+1's quads (last iter re-reads k=0; unused)
        int kn = (k + 1 < nq) ? (k + 1) : 0;
        int qn = kn*8 + s;
        float4 NX = sXq[qn], NY = sYq[qn], NZ = sZq[qn], NW = sWq[qn];

        f32x2 qx0 = {QX.x, QX.y}, qx1 = {QX.z, QX.w};
        f32x2 qy0 = {QY.x, QY.y}, qy1 = {QY.z, QY.w};
        f32x2 qz0 = {QZ.x, QZ.y}, qz1 = {QZ.z, QZ.w};
        f32x2 qw0 = {QW.x, QW.y}, qw1 = {QW.z, QW.w};
        int cb = k << 2;                 // lane-uniform (SGPR)
        #pragma unroll
        for (int j = 0; j < 4; ++j) {
          f32x2 dt0 = ((Xd[j]*qx0) + (Yd[j]*qy0)) + (Zd[j]*qz0);
          f32x2 tt0 = (C2[j] - dt0) + qw0;
          f32x2 dt1 = ((Xd[j]*qx1) + (Yd[j]*qy1)) + (Zd[j]*qz1);
          f32x2 tt1 = (C2[j] - dt1) + qw1;
          float e0 = fmaxf(tt0.x, 0.f);
          float e1 = fmaxf(tt0.y, 0.f);
          float e2 = fmaxf(tt1.x, 0.f);
          float e3 = fmaxf(tt1.y, 0.f);
          bool l0 = e0 < best[j]; best[j] = fminf(best[j], e0); code[j] = l0 ? cb       : code[j];
          bool l1 = e1 < best[j]; best[j] = fminf(best[j], e1); code[j] = l1 ? (cb | 1) : code[j];
          bool l2 = e2 < best[j]; best[j] = fminf(best[j], e2); code[j] = l2 ? (cb | 2) : code[j];
          bool l3 = e3 < best[j]; best[j] = fminf(best[j], e3); code[j] = l3 ? (cb | 3) : code[j];
        }
        QX = NX; QY = NY; QZ = NZ; QW = NW;
      }
    }
    // tail: partial 32-block (not taken when mlen % 32 == 0)
    int mb0 = nq << 5;
    if (mb0 < mlen) {
      const float* fX = (const float*)sXq; const float* fY = (const float*)sYq;
      const float* fZ = (const float*)sZq; const float* fW = (const float*)sWq;
      #pragma unroll
      for (int e = 0; e < 4; ++e) {
        int m = mb0 + 4*s + e;
        if (m < mlen) {
          float qx = fX[m], qy = fY[m], qz = fZ[m], qw = fW[m];
          int cc = (nq << 2) | e;
          #pragma unroll
          for (int j = 0; j < 4; ++j) {
            float dt2 = ((Xd[j].x*qx) + (Yd[j].x*qy)) + (Zd[j].x*qz);
            float dd = fmaxf((C2[j].x - dt2) + qw, 0.0f);
            bool lt = dd < best[j];
            best[j] = fminf(best[j], dd);
            code[j] = lt ? cc : code[j];
          }
        }
      }
    }
  }

  // merge the 8 slices (butterfly within each 8-lane group), lexicographic
  u64_t pk[4];
  #pragma unroll
  for (int j = 0; j < 4; ++j) {
    int mj = ((code[j] >> 2) << 5) + 4*s + (code[j] & 3);
    pk[j] = ((u64_t)__float_as_uint(best[j]) << 32) | (uint_t)mj;
    u64_t o;
    o = __shfl_xor(pk[j], 1); if (o < pk[j]) pk[j] = o;
    o = __shfl_xor(pk[j], 2); if (o < pk[j]) pk[j] = o;
    o = __shfl_xor(pk[j], 4); if (o < pk[j]) pk[j] = o;
  }

  // lanes s=0..3 each transform one point (no redistribution shuffles)
  if (s < 4) {
    u64_t mypk = (s==0) ? pk[0] : (s==1) ? pk[1] : (s==2) ? pk[2] : pk[3];
    float xa = (s==0) ? X[0] : (s==1) ? X[1] : (s==2) ? X[2] : X[3];
    float ya = (s==0) ? Y[0] : (s==1) ? Y[1] : (s==2) ? Y[2] : Y[3];
    float za = (s==0) ? Z[0] : (s==1) ? Z[1] : (s==2) ? Z[2] : Z[3];
    int n = n0 + s;
    int bm = (int)(mypk & 0xFFFFFFFFull);
    float bd = __uint_as_float((uint_t)(mypk >> 32));
    float pn = sqrtf(bd);
    float fl = ((double)pn < 0.08) ? 1.0f : 0.0f;
    float dxa = pose_dirs[n*3+0], dya = pose_dirs[n*3+1], dza = pose_dirs[n*3+2];
    transform_one(n, p, bm, pn, fl, xa, ya, za, dxa, dya, dza, pbw, sA4, sB4, out);
  }
}

// ---------------- MLP: 32-row passes for occupancy ----------------
// grid: 2560 blocks x 256 threads (4 waves); block = 64 rows, TWO passes of
// 32 rows. Round-11 lesson: fusion gave zero overlap (lockstep phases) and
// the sH XOR "fix" CREATED 4.26M bank conflicts (r10 non-XOR had 20K) ->
// both reverted. This round: halve the per-pass tile so sH=16KB, acc=8 regs;
// LDS 25KB -> 6 blocks/CU (was 3), roughly doubling resident waves for this
// latency-bound kernel. W2 read twice per block (655MB L2 aggregate, well
// under the 34.5TB/s ceiling). h1 exprs / sH addressing (non-XOR) / per-
// (row,col) kc order verbatim from round-10 -> h2 bit-identical; layer-3
// association identical to round-10 (passed at 0.0039 vs 0.0447 threshold).
__global__ __launch_bounds__(256) void mlp_kernel(
    const float* __restrict__ W1g, const float* __restrict__ b1g,
    const float* __restrict__ b2g, const float* __restrict__ W3g,
    const float* __restrict__ b3g, const ushort_t* __restrict__ W2bf,
    float* __restrict__ out)
{
  __shared__ __align__(16) char smem[25088];
  ushort_t* sH   = (ushort_t*)smem;                 // 16KB: [mt(2)][kc(8)][lane(64)][8]
  float4*   w1c  = (float4*)(smem + 16384);         // 4KB {W1[0][c],W1[1][c],W1[2][c],b1[c]}
  float4*   w3b2 = (float4*)(smem + 20480);         // 4KB {W3[c][0..2], b2[c]}
  float4*   sRow = (float4*)(smem + 24576);         // 512B {x,y,z,pflag} per row
  float*    prt  = (float*)smem;                    // overlay on sH: [32][4][3]

  int t = threadIdx.x;
  int wave = t >> 6, lane = t & 63, quad = lane >> 4, m16 = lane & 15;
  size_t row0 = (size_t)blockIdx.x * 64;

  {
    int c = t;   // 256 threads exactly
    w1c[c]  = make_float4(W1g[c], W1g[256+c], W1g[512+c], b1g[c]);
    w3b2[c] = make_float4(W3g[c*3+0], W3g[c*3+1], W3g[c*3+2], b2g[c]);
  }

  #pragma unroll 1
  for (int pass = 0; pass < 2; ++pass) {
    size_t rbase = row0 + pass*32;
    if (t < 32) {
      size_t r = rbase + t;
      sRow[t] = make_float4(out[O4 + r*3+0], out[O4 + r*3+1], out[O4 + r*3+2],
                            out[O3 + r]);
    }
    __syncthreads();   // sRow (+ params on pass 0) visible; prev pass fully done

    // build sH: thread t -> col-octet q8 = t&31 (kcw=q8>>2, qd=q8&3),
    // rows rg*4 .. rg*4+3 (rg = t>>5). r10-verbatim h1 exprs, non-XOR slots.
    {
      int q8 = t & 31, rg = t >> 5;
      int kcw = q8 >> 2, qd = q8 & 3;
      int c0 = kcw*32 + qd*8;
      float4 wv[8];
      #pragma unroll
      for (int j = 0; j < 8; ++j) wv[j] = w1c[c0 + j];
      #pragma unroll
      for (int rr = 0; rr < 4; ++rr) {
        int r = rg*4 + rr;           // 0..31
        float4 xyz = sRow[r];
        uint_t u0, u1, u2, u3;
        {
          float4 wA = wv[0], wB = wv[1];
          float hA = fmaxf(fmaf(xyz.z, wA.z, fmaf(xyz.y, wA.y, fmaf(xyz.x, wA.x, wA.w))), 0.f);
          float hB = fmaxf(fmaf(xyz.z, wB.z, fmaf(xyz.y, wB.y, fmaf(xyz.x, wB.x, wB.w))), 0.f);
          u0 = cvt_pk_bf16(hA, hB);
        }
        {
          float4 wA = wv[2], wB = wv[3];
          float hA = fmaxf(fmaf(xyz.z, wA.z, fmaf(xyz.y, wA.y, fmaf(xyz.x, wA.x, wA.w))), 0.f);
          float hB = fmaxf(fmaf(xyz.z, wB.z, fmaf(xyz.y, wB.y, fmaf(xyz.x, wB.x, wB.w))), 0.f);
          u1 = cvt_pk_bf16(hA, hB);
        }
        {
          float4 wA = wv[4], wB = wv[5];
          float hA = fmaxf(fmaf(xyz.z, wA.z, fmaf(xyz.y, wA.y, fmaf(xyz.x, wA.x, wA.w))), 0.f);
          float hB = fmaxf(fmaf(xyz.z, wB.z, fmaf(xyz.y, wB.y, fmaf(xyz.x, wB.x, wB.w))), 0.f);
          u2 = cvt_pk_bf16(hA, hB);
        }
        {
          float4 wA = wv[6], wB = wv[7];
          float hA = fmaxf(fmaf(xyz.z, wA.z, fmaf(xyz.y, wA.y, fmaf(xyz.x, wA.x, wA.w))), 0.f);
          float hB = fmaxf(fmaf(xyz.z, wB.z, fmaf(xyz.y, wB.y, fmaf(xyz.x, wB.x, wB.w))), 0.f);
          u3 = cvt_pk_bf16(hA, hB);
        }
        int mt = r >> 4, r15 = r & 15;
        int l = qd*16 + r15;        // round-10 non-XOR layout (20K conflicts)
        *(uint4*)(&sH[((mt*8 + kcw)*64 + l)*8]) = make_uint4(u0, u1, u2, u3);
      }
    }
    __syncthreads();

    // K-loop: wave owns cols nt in [wave*4, wave*4+4)
    const ushort_t* Wlane = W2bf + (size_t)wave*2048 + lane*8;
    bf16x8 Bcur[4], Bnxt[4];
    #pragma unroll
    for (int q = 0; q < 4; ++q) Bcur[q] = *(const bf16x8*)(Wlane + q*512);  // kc=0

    f32x4 acc[8];                    // acc[mt*4+q], mt in 0..1
    #pragma unroll
    for (int i = 0; i < 8; ++i) acc[i] = (f32x4){0.f,0.f,0.f,0.f};

    #pragma unroll 1
    for (int kc = 0; kc < 8; ++kc) {
      bf16x8 Af[2];
      #pragma unroll
      for (int mt = 0; mt < 2; ++mt)
        Af[mt] = *(const bf16x8*)(&sH[((mt*8 + kc)*64 + lane)*8]);
      if (kc < 7) {                  // prefetch next kc's B under this kc's MFMAs
        #pragma unroll
        for (int q = 0; q < 4; ++q)
          Bnxt[q] = *(const bf16x8*)(Wlane + (kc+1)*8192 + q*512);
      }
      #pragma unroll
      for (int mt = 0; mt < 2; ++mt)
        #pragma unroll
        for (int q = 0; q < 4; ++q)
          acc[mt*4+q] = __builtin_amdgcn_mfma_f32_16x16x32_bf16(Af[mt], Bcur[q], acc[mt*4+q], 0, 0, 0);
      if (kc < 7) {
        #pragma unroll
        for (int q = 0; q < 4; ++q) Bcur[q] = Bnxt[q];
      }
    }
    __syncthreads();   // all waves done reading sH -> prt overlay safe

    // epilogue: h2[row=mt*16+quad*4+reg][col=(wave*4+q)*16+m16] = acc[mt*4+q][reg]
    float4 cvq[4];
    #pragma unroll
    for (int q = 0; q < 4; ++q) cvq[q] = w3b2[(wave*4+q)*16 + m16];

    #pragma unroll
    for (int mt = 0; mt < 2; ++mt) {
      #pragma unroll
      for (int reg = 0; reg < 4; ++reg) {
        float q0 = 0.f, q1 = 0.f, q2 = 0.f;
        #pragma unroll
        for (int q = 0; q < 4; ++q) {
          float h2 = fmaxf(acc[mt*4+q][reg] + cvq[q].w, 0.f);
          q0 = fmaf(h2, cvq[q].x, q0);
          q1 = fmaf(h2, cvq[q].y, q1);
          q2 = fmaf(h2, cvq[q].z, q2);
        }
        q0 = dpp_sum16(q0);
        q1 = dpp_sum16(q1);
        q2 = dpp_sum16(q2);
        if (m16 == 0) {
          int lr = mt*16 + quad*4 + reg;           // local row 0..31
          prt[(lr*4 + wave)*3 + 0] = q0;
          prt[(lr*4 + wave)*3 + 1] = q1;
          prt[(lr*4 + wave)*3 + 2] = q2;
        }
      }
    }
    __syncthreads();

    // combine: thread t<128 -> (row = t>>2, comp = t&3), comp<3 active
    if (t < 128) {
      int lr = t >> 2, c = t & 3;
      if (c < 3) {
        float v = ((prt[(lr*4+0)*3+c] + prt[(lr*4+1)*3+c]) + prt[(lr*4+2)*3+c]) + prt[(lr*4+3)*3+c];
        size_t r = rbase + lr;
        float4 ib = sRow[lr];
        float iv = (c == 0) ? ib.x : (c == 1) ? ib.y : ib.z;
        float rr = 0.05f * tanh_fast(v + b3g[c]) * ib.w;
        out[O0 + r*3 + c] = iv + rr;
        out[O2 + r*3 + c] = rr;
      }
    }
    __syncthreads();   // combine's sRow/prt reads done before next pass writes
  }
}

extern "C" void kernel_launch(void* const* d_in, const int* in_sizes, int n_in,
                              void* d_out, int out_size, void* d_ws, size_t ws_size,
                              hipStream_t stream) {
  (void)out_size; (void)ws_size;
  // size-based slot remap (no-op under documented dict order; protective otherwise)
  const int want[13] = {98304, 98304, 15360, 122880, 384, 384, 768, 256, 65536, 256, 768, 3, 5};
  int idx[13];
  bool used[64] = {false};
  for (int L = 0; L < 13; ++L) {
    idx[L] = -1;
    for (int s = 0; s < n_in && s < 64; ++s) {
      if (!used[s] && in_sizes[s] == want[L]) { idx[L] = s; used[s] = true; break; }
    }
    if (idx[L] < 0) idx[L] = L;
  }
  const float* pp0       = (const float*)d_in[idx[0]];
  const float* pp1       = (const float*)d_in[idx[1]];
  const float* part_pts  = (const float*)d_in[idx[2]];
  const float* part_pbw  = (const float*)d_in[idx[3]];
  const float* A         = (const float*)d_in[idx[4]];
  const float* bigA      = (const float*)d_in[idx[5]];
  const float* W1        = (const float*)d_in[idx[6]];
  const float* b1        = (const float*)d_in[idx[7]];
  const float* W2        = (const float*)d_in[idx[8]];
  const float* b2        = (const float*)d_in[idx[9]];
  const float* W3        = (const float*)d_in[idx[10]];
  const float* b3        = (const float*)d_in[idx[11]];
  const int*   lengths2  = (const int*)d_in[idx[12]];
  float* out = (float*)d_out;
  ushort_t* W2bf = (ushort_t*)d_ws;   // 128 KB of workspace

  nn_kernel<<<1536, 256, 0, stream>>>(pp0, pp1, part_pts, part_pbw,
                                      A, bigA, lengths2, W2, W2bf, out);
  mlp_kernel<<<2560, 256, 0, stream>>>(W1, b1, b2, W3, b3, W2bf, out);
}

// Round 13
// 170.159 us; speedup vs baseline: 1.0054x; 1.0053x over previous
//
#include <hip/hip_runtime.h>
#include <stdint.h>
#include <math.h>

// Problem constants
#define NPTS 32768
#define PP   5
#define MM   1024
#define JJ   24
#define HH   256

// out (f32 element offsets), total 2,293,760 floats
#define O0 0                // tpose        [1,N,P,3]
#define O1 491520           // tpose_dirs   [1,N,P,3]
#define O2 983040           // resd         [1,N,P,3]
#define O3 1474560          // pflag        [1,N,P]
#define O4 1638400          // init_bigpose [1,N*P,3]
#define O5 2129920          // pnorm        [1,N*P]

typedef unsigned short ushort_t;
typedef unsigned int   uint_t;
typedef unsigned long long u64_t;
typedef __attribute__((ext_vector_type(8))) short bf16x8;
typedef __attribute__((ext_vector_type(4))) float f32x4;
typedef __attribute__((ext_vector_type(2))) float f32x2;

__device__ __forceinline__ ushort_t f2bf(float f) {
  union { uint_t i; float f; } v; v.f = f;
  uint_t i = v.i;
  return (ushort_t)((i + 0x7FFFu + ((i >> 16) & 1u)) >> 16);  // RNE
}
// hardware packed f32->bf16 (RNE, bit-identical to f2bf for finite values)
__device__ __forceinline__ uint_t cvt_pk_bf16(float lo, float hi) {
  uint_t r;
  asm("v_cvt_pk_bf16_f32 %0, %1, %2" : "=v"(r) : "v"(lo), "v"(hi));
  return r;
}
__device__ __forceinline__ float tanh_fast(float v) {
  v = fminf(fmaxf(v, -15.f), 15.f);
  float e = __expf(2.f*v);               // v_exp_f32 path
  return __fdividef(e - 1.f, e + 1.f);   // abs err < 1e-6, plenty for tolerance
}
// 16-lane sum via DPP row_shl tree (VALU pipe). Result in lane m16==0.
__device__ __forceinline__ float dpp_sum16(float x) {
  x += __int_as_float(__builtin_amdgcn_update_dpp(0, __float_as_int(x), 0x108, 0xF, 0xF, true)); // row_shl:8
  x += __int_as_float(__builtin_amdgcn_update_dpp(0, __float_as_int(x), 0x104, 0xF, 0xF, true)); // row_shl:4
  x += __int_as_float(__builtin_amdgcn_update_dpp(0, __float_as_int(x), 0x102, 0xF, 0xF, true)); // row_shl:2
  x += __int_as_float(__builtin_amdgcn_update_dpp(0, __float_as_int(x), 0x101, 0xF, 0xF, true)); // row_shl:1
  return x;
}

// ---------------- LBS transform for one (n,p) row ----------------
__device__ __forceinline__ void transform_one(
    int n, int p, int nn, float pn, float fl,
    float px, float py, float pz, float dx, float dy, float dz,
    const float* __restrict__ pbw,
    const float4* __restrict__ sA4, const float4* __restrict__ sB4,
    float* __restrict__ out)
{
  const float4* bwr = (const float4*)(pbw + ((size_t)p * MM + nn) * JJ);
  float bw[24];
  #pragma unroll
  for (int q = 0; q < 6; ++q) {
    float4 u = bwr[q];
    bw[q*4+0] = u.x; bw[q*4+1] = u.y; bw[q*4+2] = u.z; bw[q*4+3] = u.w;
  }

  float M1[12], M2[12];
  #pragma unroll
  for (int q = 0; q < 12; ++q) { M1[q] = 0.f; M2[q] = 0.f; }
  #pragma unroll
  for (int j = 0; j < 24; ++j) {
    float w = bw[j];
    float4 a0 = sA4[j*3+0], a1 = sA4[j*3+1], a2 = sA4[j*3+2];
    M1[0]=fmaf(w,a0.x,M1[0]); M1[1]=fmaf(w,a0.y,M1[1]); M1[2]=fmaf(w,a0.z,M1[2]); M1[3]=fmaf(w,a0.w,M1[3]);
    M1[4]=fmaf(w,a1.x,M1[4]); M1[5]=fmaf(w,a1.y,M1[5]); M1[6]=fmaf(w,a1.z,M1[6]); M1[7]=fmaf(w,a1.w,M1[7]);
    M1[8]=fmaf(w,a2.x,M1[8]); M1[9]=fmaf(w,a2.y,M1[9]); M1[10]=fmaf(w,a2.z,M1[10]); M1[11]=fmaf(w,a2.w,M1[11]);
    float4 c0 = sB4[j*3+0], c1 = sB4[j*3+1], c2 = sB4[j*3+2];
    M2[0]=fmaf(w,c0.x,M2[0]); M2[1]=fmaf(w,c0.y,M2[1]); M2[2]=fmaf(w,c0.z,M2[2]); M2[3]=fmaf(w,c0.w,M2[3]);
    M2[4]=fmaf(w,c1.x,M2[4]); M2[5]=fmaf(w,c1.y,M2[5]); M2[6]=fmaf(w,c1.z,M2[6]); M2[7]=fmaf(w,c1.w,M2[7]);
    M2[8]=fmaf(w,c2.x,M2[8]); M2[9]=fmaf(w,c2.y,M2[9]); M2[10]=fmaf(w,c2.z,M2[10]); M2[11]=fmaf(w,c2.w,M2[11]);
  }
  float a=M1[0], b=M1[1], c=M1[2];
  float d=M1[4], e=M1[5], f=M1[6];
  float g=M1[8], h=M1[9], i=M1[10];
  float C00 = e*i - f*h, C01 = c*h - b*i, C02 = b*f - c*e;
  float C10 = f*g - d*i, C11 = a*i - c*g, C12 = c*d - a*f;
  float C20 = d*h - e*g, C21 = b*g - a*h, C22 = a*e - b*d;
  float det = a*C00 + b*C10 + c*C20;
  float rd = 1.0f / det;
  float tx = px - M1[3], ty = py - M1[7], tz = pz - M1[11];
  float t0 = rd * (C00*tx + C01*ty + C02*tz);
  float t1 = rd * (C10*tx + C11*ty + C12*tz);
  float t2 = rd * (C20*tx + C21*ty + C22*tz);
  float i0 = M2[0]*t0 + M2[1]*t1 + M2[2]*t2  + M2[3];
  float i1 = M2[4]*t0 + M2[5]*t1 + M2[6]*t2  + M2[7];
  float i2 = M2[8]*t0 + M2[9]*t1 + M2[10]*t2 + M2[11];
  float d0 = rd * (C00*dx + C01*dy + C02*dz);
  float d1 = rd * (C10*dx + C11*dy + C12*dz);
  float d2 = rd * (C20*dx + C21*dy + C22*dz);
  float e0 = M2[0]*d0 + M2[1]*d1 + M2[2]*d2;
  float e1 = M2[4]*d0 + M2[5]*d1 + M2[6]*d2;
  float e2 = M2[8]*d0 + M2[9]*d1 + M2[10]*d2;

  size_t k = (size_t)n * PP + p;   // n-major
  out[O1 + k*3+0] = e0; out[O1 + k*3+1] = e1; out[O1 + k*3+2] = e2;
  out[O3 + k] = fl;
  out[O4 + k*3+0] = i0; out[O4 + k*3+1] = i1; out[O4 + k*3+2] = i2;
  out[O5 + k] = pn;
}

// grid: 1536 blocks x 256 threads. Blocks >=1280 do the W2->bf16 prep.
// Blocks <1280: p = b>>8, 128 n's; r6-verified structure (no manual prefetch —
// r12's pipelining regressed) with a cheaper argmin: per 32-block the 4
// clamped distances reduce via a 3-op fminf tree, then ONE fminf+cmp+cndmask
// tracks (best, block-id). The exact first-min INDEX is recovered afterward
// by re-scanning only the winning block with the bit-identical expression
// (deterministic replay: first element == best is the first min). Tail
// elements update (best, m) with strict < (tail m's larger -> equality keeps
// the earlier index). Semantics identical to the verified r6 argmin.
__global__ __launch_bounds__(256) void nn_kernel(
    const float* __restrict__ pp0, const float* __restrict__ pp1,
    const float* __restrict__ part_pts, const float* __restrict__ pbw,
    const float* __restrict__ Ag, const float* __restrict__ Bg,
    const int* __restrict__ lengths2,
    const float* __restrict__ W2g, ushort_t* __restrict__ W2bf,
    float* __restrict__ out)
{
  // folded W2 prep (former prep_w2): blocks 1280..1535, k = bid-1280
  if (blockIdx.x >= 1280) {
    int k = blockIdx.x - 1280;
    int n = threadIdx.x;
    float v = W2g[k*256 + n];
    int kc = k >> 5, quad = (k & 31) >> 3, j = k & 7;
    int tile = n >> 4, lane = quad*16 + (n & 15);
    W2bf[kc*8192 + tile*512 + lane*8 + j] = f2bf(v);
    return;
  }

  __shared__ float4 sXq[256], sYq[256], sZq[256], sWq[256];  // SoA quads
  __shared__ float4 sA4[72];
  __shared__ float4 sB4[72];
  int t = threadIdx.x;
  int p  = blockIdx.x >> 8;        // 256 blocks per part
  int nb = blockIdx.x & 255;
  int g  = t >> 3;                 // n-group 0..31
  int s  = t & 7;                  // m-slice 0..7
  int n0 = nb*128 + g*4;           // this lane's 4 points: n0..n0+3

  // pose-pair disambiguation (wave-uniform); pose_dirs rows unit-norm
  float s0r0 = pp0[0], s0r1 = pp0[1], s0r2 = pp0[2];
  float nrm = s0r0*s0r0 + s0r1*s0r1 + s0r2*s0r2;
  bool c0_is_dirs = fabsf(nrm - 1.0f) < 1e-4f;
  const float* pose_pts  = c0_is_dirs ? pp1 : pp0;
  const float* pose_dirs = c0_is_dirs ? pp0 : pp1;

  {
    #pragma clang fp contract(off)
    float* fX = (float*)sXq; float* fY = (float*)sYq;
    float* fZ = (float*)sZq; float* fW = (float*)sWq;
    for (int i = t; i < MM; i += 256) {
      float x = part_pts[((size_t)p*MM+i)*3+0];
      float y = part_pts[((size_t)p*MM+i)*3+1];
      float z = part_pts[((size_t)p*MM+i)*3+2];
      float yy = ((x*x) + (y*y)) + (z*z);
      fX[i] = x; fY[i] = y; fZ[i] = z; fW[i] = yy;
    }
  }
  for (int i = t; i < 72; i += 256) {
    int l = i*4;
    int j = l / 12, rc = l % 12;
    float4 qa, qb;
    qa.x = Ag[j*16+rc+0]; qa.y = Ag[j*16+rc+1]; qa.z = Ag[j*16+rc+2]; qa.w = Ag[j*16+rc+3];
    qb.x = Bg[j*16+rc+0]; qb.y = Bg[j*16+rc+1]; qb.z = Bg[j*16+rc+2]; qb.w = Bg[j*16+rc+3];
    sA4[i] = qa; sB4[i] = qb;
  }
  int mlen = lengths2[p]; if (mlen > MM) mlen = MM;
  __syncthreads();

  // load 4 points' coordinates (n0 % 4 == 0 -> 16B aligned); build doubled splats
  float X[4], Y[4], Z[4];
  f32x2 Xd[4], Yd[4], Zd[4], C2[4];
  {
    #pragma clang fp contract(off)
    const float4* pr = (const float4*)(pose_pts + (size_t)n0*3);
    float4 f0 = pr[0], f1 = pr[1], f2 = pr[2];
    X[0]=f0.x; Y[0]=f0.y; Z[0]=f0.z;
    X[1]=f0.w; Y[1]=f1.x; Z[1]=f1.y;
    X[2]=f1.z; Y[2]=f1.w; Z[2]=f2.x;
    X[3]=f2.y; Y[3]=f2.z; Z[3]=f2.w;
    #pragma unroll
    for (int j = 0; j < 4; ++j) {
      float x2 = ((X[j]*X[j]) + (Y[j]*Y[j])) + (Z[j]*Z[j]);
      Xd[j] = (f32x2){2.0f*X[j], 2.0f*X[j]};
      Yd[j] = (f32x2){2.0f*Y[j], 2.0f*Y[j]};
      Zd[j] = (f32x2){2.0f*Z[j], 2.0f*Z[j]};
      C2[j] = (f32x2){x2, x2};
    }
  }

  float best[4]  = {INFINITY, INFINITY, INFINITY, INFINITY};
  int   kb[4]    = {0, 0, 0, 0};   // winning 32-block id (main scan)
  int   mbest[4] = {0, 0, 0, 0};   // final m index
  int   nq = mlen >> 5;            // full 32-blocks
  {
    #pragma clang fp contract(off)
    for (int k = 0; k < nq; ++k) {
      int qi = k*8 + s;                // quad index (8-way same-addr broadcast)
      float4 QX = sXq[qi], QY = sYq[qi], QZ = sZq[qi], QW = sWq[qi];
      f32x2 qx0 = {QX.x, QX.y}, qx1 = {QX.z, QX.w};
      f32x2 qy0 = {QY.x, QY.y}, qy1 = {QY.z, QY.w};
      f32x2 qz0 = {QZ.x, QZ.y}, qz1 = {QZ.z, QZ.w};
      f32x2 qw0 = {QW.x, QW.y}, qw1 = {QW.z, QW.w};
      #pragma unroll
      for (int j = 0; j < 4; ++j) {
        f32x2 dt0 = ((Xd[j]*qx0) + (Yd[j]*qy0)) + (Zd[j]*qz0);
        f32x2 tt0 = (C2[j] - dt0) + qw0;
        f32x2 dt1 = ((Xd[j]*qx1) + (Yd[j]*qy1)) + (Zd[j]*qz1);
        f32x2 tt1 = (C2[j] - dt1) + qw1;
        float e0 = fmaxf(tt0.x, 0.f);
        float e1 = fmaxf(tt0.y, 0.f);
        float e2 = fmaxf(tt1.x, 0.f);
        float e3 = fmaxf(tt1.y, 0.f);
        float m01 = fminf(e0, e1);
        float m23 = fminf(e2, e3);
        float lmin = fminf(m01, m23);
        bool lt = lmin < best[j];            // strict: first block keeps win
        best[j] = fminf(best[j], lmin);
        kb[j] = lt ? k : kb[j];
      }
    }
    // deterministic replay of the winning block -> exact first-min index
    if (nq > 0) {
      #pragma unroll
      for (int j = 0; j < 4; ++j) {
        int qi = kb[j]*8 + s;
        float4 QX = sXq[qi], QY = sYq[qi], QZ = sZq[qi], QW = sWq[qi];
        float dA = ((Xd[j].x*QX.x) + (Yd[j].x*QY.x)) + (Zd[j].x*QZ.x);
        float eA = fmaxf((C2[j].x - dA) + QW.x, 0.f);
        float dB = ((Xd[j].x*QX.y) + (Yd[j].x*QY.y)) + (Zd[j].x*QZ.y);
        float eB = fmaxf((C2[j].x - dB) + QW.y, 0.f);
        float dC = ((Xd[j].x*QX.z) + (Yd[j].x*QY.z)) + (Zd[j].x*QZ.z);
        float eC = fmaxf((C2[j].x - dC) + QW.z, 0.f);
        // first element equal to best (eD implied if others miss)
        int e = (eA == best[j]) ? 0 : (eB == best[j]) ? 1 : (eC == best[j]) ? 2 : 3;
        mbest[j] = (kb[j] << 5) + 4*s + e;
      }
    } else {
      #pragma unroll
      for (int j = 0; j < 4; ++j) mbest[j] = 4*s;
    }
    // tail: partial 32-block (not taken when mlen % 32 == 0)
    int mb0 = nq << 5;
    if (mb0 < mlen) {
      const float* fX = (const float*)sXq; const float* fY = (const float*)sYq;
      const float* fZ = (const float*)sZq; const float* fW = (const float*)sWq;
      #pragma unroll
      for (int e = 0; e < 4; ++e) {
        int m = mb0 + 4*s + e;
        if (m < mlen) {
          float qx = fX[m], qy = fY[m], qz = fZ[m], qw = fW[m];
          #pragma unroll
          for (int j = 0; j < 4; ++j) {
            float dt2 = ((Xd[j].x*qx) + (Yd[j].x*qy)) + (Zd[j].x*qz);
            float dd = fmaxf((C2[j].x - dt2) + qw, 0.0f);
            bool lt = dd < best[j];          // strict: earlier m wins ties
            best[j] = fminf(best[j], dd);
            mbest[j] = lt ? m : mbest[j];
          }
        }
      }
    }
  }

  // merge the 8 slices (butterfly within each 8-lane group), lexicographic
  u64_t pk[4];
  #pragma unroll
  for (int j = 0; j < 4; ++j) {
    pk[j] = ((u64_t)__float_as_uint(best[j]) << 32) | (uint_t)mbest[j];
    u64_t o;
    o = __shfl_xor(pk[j], 1); if (o < pk[j]) pk[j] = o;
    o = __shfl_xor(pk[j], 2); if (o < pk[j]) pk[j] = o;
    o = __shfl_xor(pk[j], 4); if (o < pk[j]) pk[j] = o;
  }

  // lanes s=0..3 each transform one point (no redistribution shuffles)
  if (s < 4) {
    u64_t mypk = (s==0) ? pk[0] : (s==1) ? pk[1] : (s==2) ? pk[2] : pk[3];
    float xa = (s==0) ? X[0] : (s==1) ? X[1] : (s==2) ? X[2] : X[3];
    float ya = (s==0) ? Y[0] : (s==1) ? Y[1] : (s==2) ? Y[2] : Y[3];
    float za = (s==0) ? Z[0] : (s==1) ? Z[1] : (s==2) ? Z[2] : Z[3];
    int n = n0 + s;
    int bm = (int)(mypk & 0xFFFFFFFFull);
    float bd = __uint_as_float((uint_t)(mypk >> 32));
    float pn = sqrtf(bd);
    float fl = ((double)pn < 0.08) ? 1.0f : 0.0f;
    float dxa = pose_dirs[n*3+0], dya = pose_dirs[n*3+1], dza = pose_dirs[n*3+2];
    transform_one(n, p, bm, pn, fl, xa, ya, za, dxa, dya, dza, pbw, sA4, sB4, out);
  }
}

// ---------------- MLP: 32-row passes, 128 rows/block ----------------
// grid: 1280 blocks x 256 threads (4 waves); block = 128 rows, FOUR passes of
// 32 rows (r12-verified pass structure verbatim). 128 rows/block halves W2 L2
// traffic vs r12 (655 -> 327 MB) and quarters the param-preamble count.
// LDS 25KB -> 6 blocks/CU by LDS; 1280 blocks = 5/CU exactly.
__global__ __launch_bounds__(256) void mlp_kernel(
    const float* __restrict__ W1g, const float* __restrict__ b1g,
    const float* __restrict__ b2g, const float* __restrict__ W3g,
    const float* __restrict__ b3g, const ushort_t* __restrict__ W2bf,
    float* __restrict__ out)
{
  __shared__ __align__(16) char smem[25088];
  ushort_t* sH   = (ushort_t*)smem;                 // 16KB: [mt(2)][kc(8)][lane(64)][8]
  float4*   w1c  = (float4*)(smem + 16384);         // 4KB {W1[0][c],W1[1][c],W1[2][c],b1[c]}
  float4*   w3b2 = (float4*)(smem + 20480);         // 4KB {W3[c][0..2], b2[c]}
  float4*   sRow = (float4*)(smem + 24576);         // 512B {x,y,z,pflag} per row
  float*    prt  = (float*)smem;                    // overlay on sH: [32][4][3]

  int t = threadIdx.x;
  int wave = t >> 6, lane = t & 63, quad = lane >> 4, m16 = lane & 15;
  size_t row0 = (size_t)blockIdx.x * 128;

  {
    int c = t;   // 256 threads exactly
    w1c[c]  = make_float4(W1g[c], W1g[256+c], W1g[512+c], b1g[c]);
    w3b2[c] = make_float4(W3g[c*3+0], W3g[c*3+1], W3g[c*3+2], b2g[c]);
  }

  #pragma unroll 1
  for (int pass = 0; pass < 4; ++pass) {
    size_t rbase = row0 + pass*32;
    if (t < 32) {
      size_t r = rbase + t;
      sRow[t] = make_float4(out[O4 + r*3+0], out[O4 + r*3+1], out[O4 + r*3+2],
                            out[O3 + r]);
    }
    __syncthreads();   // sRow (+ params on pass 0) visible; prev pass fully done

    // build sH: thread t -> col-octet q8 = t&31 (kcw=q8>>2, qd=q8&3),
    // rows rg*4 .. rg*4+3 (rg = t>>5). r10-verbatim h1 exprs, non-XOR slots.
    {
      int q8 = t & 31, rg = t >> 5;
      int kcw = q8 >> 2, qd = q8 & 3;
      int c0 = kcw*32 + qd*8;
      float4 wv[8];
      #pragma unroll
      for (int j = 0; j < 8; ++j) wv[j] = w1c[c0 + j];
      #pragma unroll
      for (int rr = 0; rr < 4; ++rr) {
        int r = rg*4 + rr;           // 0..31
        float4 xyz = sRow[r];
        uint_t u0, u1, u2, u3;
        {
          float4 wA = wv[0], wB = wv[1];
          float hA = fmaxf(fmaf(xyz.z, wA.z, fmaf(xyz.y, wA.y, fmaf(xyz.x, wA.x, wA.w))), 0.f);
          float hB = fmaxf(fmaf(xyz.z, wB.z, fmaf(xyz.y, wB.y, fmaf(xyz.x, wB.x, wB.w))), 0.f);
          u0 = cvt_pk_bf16(hA, hB);
        }
        {
          float4 wA = wv[2], wB = wv[3];
          float hA = fmaxf(fmaf(xyz.z, wA.z, fmaf(xyz.y, wA.y, fmaf(xyz.x, wA.x, wA.w))), 0.f);
          float hB = fmaxf(fmaf(xyz.z, wB.z, fmaf(xyz.y, wB.y, fmaf(xyz.x, wB.x, wB.w))), 0.f);
          u1 = cvt_pk_bf16(hA, hB);
        }
        {
          float4 wA = wv[4], wB = wv[5];
          float hA = fmaxf(fmaf(xyz.z, wA.z, fmaf(xyz.y, wA.y, fmaf(xyz.x, wA.x, wA.w))), 0.f);
          float hB = fmaxf(fmaf(xyz.z, wB.z, fmaf(xyz.y, wB.y, fmaf(xyz.x, wB.x, wB.w))), 0.f);
          u2 = cvt_pk_bf16(hA, hB);
        }
        {
          float4 wA = wv[6], wB = wv[7];
          float hA = fmaxf(fmaf(xyz.z, wA.z, fmaf(xyz.y, wA.y, fmaf(xyz.x, wA.x, wA.w))), 0.f);
          float hB = fmaxf(fmaf(xyz.z, wB.z, fmaf(xyz.y, wB.y, fmaf(xyz.x, wB.x, wB.w))), 0.f);
          u3 = cvt_pk_bf16(hA, hB);
        }
        int mt = r >> 4, r15 = r & 15;
        int l = qd*16 + r15;        // round-10 non-XOR layout (20K conflicts)
        *(uint4*)(&sH[((mt*8 + kcw)*64 + l)*8]) = make_uint4(u0, u1, u2, u3);
      }
    }
    __syncthreads();

    // K-loop: wave owns cols nt in [wave*4, wave*4+4)
    const ushort_t* Wlane = W2bf + (size_t)wave*2048 + lane*8;
    bf16x8 Bcur[4], Bnxt[4];
    #pragma unroll
    for (int q = 0; q < 4; ++q) Bcur[q] = *(const bf16x8*)(Wlane + q*512);  // kc=0

    f32x4 acc[8];                    // acc[mt*4+q], mt in 0..1
    #pragma unroll
    for (int i = 0; i < 8; ++i) acc[i] = (f32x4){0.f,0.f,0.f,0.f};

    #pragma unroll 1
    for (int kc = 0; kc < 8; ++kc) {
      bf16x8 Af[2];
      #pragma unroll
      for (int mt = 0; mt < 2; ++mt)
        Af[mt] = *(const bf16x8*)(&sH[((mt*8 + kc)*64 + lane)*8]);
      if (kc < 7) {                  // prefetch next kc's B under this kc's MFMAs
        #pragma unroll
        for (int q = 0; q < 4; ++q)
          Bnxt[q] = *(const bf16x8*)(Wlane + (kc+1)*8192 + q*512);
      }
      #pragma unroll
      for (int mt = 0; mt < 2; ++mt)
        #pragma unroll
        for (int q = 0; q < 4; ++q)
          acc[mt*4+q] = __builtin_amdgcn_mfma_f32_16x16x32_bf16(Af[mt], Bcur[q], acc[mt*4+q], 0, 0, 0);
      if (kc < 7) {
        #pragma unroll
        for (int q = 0; q < 4; ++q) Bcur[q] = Bnxt[q];
      }
    }
    __syncthreads();   // all waves done reading sH -> prt overlay safe

    // epilogue: h2[row=mt*16+quad*4+reg][col=(wave*4+q)*16+m16] = acc[mt*4+q][reg]
    float4 cvq[4];
    #pragma unroll
    for (int q = 0; q < 4; ++q) cvq[q] = w3b2[(wave*4+q)*16 + m16];

    #pragma unroll
    for (int mt = 0; mt < 2; ++mt) {
      #pragma unroll
      for (int reg = 0; reg < 4; ++reg) {
        float q0 = 0.f, q1 = 0.f, q2 = 0.f;
        #pragma unroll
        for (int q = 0; q < 4; ++q) {
          float h2 = fmaxf(acc[mt*4+q][reg] + cvq[q].w, 0.f);
          q0 = fmaf(h2, cvq[q].x, q0);
          q1 = fmaf(h2, cvq[q].y, q1);
          q2 = fmaf(h2, cvq[q].z, q2);
        }
        q0 = dpp_sum16(q0);
        q1 = dpp_sum16(q1);
        q2 = dpp_sum16(q2);
        if (m16 == 0) {
          int lr = mt*16 + quad*4 + reg;           // local row 0..31
          prt[(lr*4 + wave)*3 + 0] = q0;
          prt[(lr*4 + wave)*3 + 1] = q1;
          prt[(lr*4 + wave)*3 + 2] = q2;
        }
      }
    }
    __syncthreads();

    // combine: thread t<128 -> (row = t>>2, comp = t&3), comp<3 active
    if (t < 128) {
      int lr = t >> 2, c = t & 3;
      if (c < 3) {
        float v = ((prt[(lr*4+0)*3+c] + prt[(lr*4+1)*3+c]) + prt[(lr*4+2)*3+c]) + prt[(lr*4+3)*3+c];
        size_t r = rbase + lr;
        float4 ib = sRow[lr];
        float iv = (c == 0) ? ib.x : (c == 1) ? ib.y : ib.z;
        float rr = 0.05f * tanh_fast(v + b3g[c]) * ib.w;
        out[O0 + r*3 + c] = iv + rr;
        out[O2 + r*3 + c] = rr;
      }
    }
    __syncthreads();   // combine's sRow/prt reads done before next pass writes
  }
}

extern "C" void kernel_launch(void* const* d_in, const int* in_sizes, int n_in,
                              void* d_out, int out_size, void* d_ws, size_t ws_size,
                              hipStream_t stream) {
  (void)out_size; (void)ws_size;
  // size-based slot remap (no-op under documented dict order; protective otherwise)
  const int want[13] = {98304, 98304, 15360, 122880, 384, 384, 768, 256, 65536, 256, 768, 3, 5};
  int idx[13];
  bool used[64] = {false};
  for (int L = 0; L < 13; ++L) {
    idx[L] = -1;
    for (int s = 0; s < n_in && s < 64; ++s) {
      if (!used[s] && in_sizes[s] == want[L]) { idx[L] = s; used[s] = true; break; }
    }
    if (idx[L] < 0) idx[L] = L;
  }
  const float* pp0       = (const float*)d_in[idx[0]];
  const float* pp1       = (const float*)d_in[idx[1]];
  const float* part_pts  = (const float*)d_in[idx[2]];
  const float* part_pbw  = (const float*)d_in[idx[3]];
  const float* A         = (const float*)d_in[idx[4]];
  const float* bigA      = (const float*)d_in[idx[5]];
  const float* W1        = (const float*)d_in[idx[6]];
  const float* b1        = (const float*)d_in[idx[7]];
  const float* W2        = (const float*)d_in[idx[8]];
  const float* b2        = (const float*)d_in[idx[9]];
  const float* W3        = (const float*)d_in[idx[10]];
  const float* b3        = (const float*)d_in[idx[11]];
  const int*   lengths2  = (const int*)d_in[idx[12]];
  float* out = (float*)d_out;
  ushort_t* W2bf = (ushort_t*)d_ws;   // 128 KB of workspace

  nn_kernel<<<1536, 256, 0, stream>>>(pp0, pp1, part_pts, part_pbw,
                                      A, bigA, lengths2, W2, W2bf, out);
  mlp_kernel<<<1280, 256, 0, stream>>>(W1, b1, b2, W3, b3, W2bf, out);
}

// Round 14
// 159.577 us; speedup vs baseline: 1.0721x; 1.0663x over previous
//
#include <hip/hip_runtime.h>
#include <stdint.h>
#include <math.h>

// Problem constants
#define NPTS 32768
#define PP   5
#define MM   1024
#define JJ   24
#define HH   256

// out (f32 element offsets), total 2,293,760 floats
#define O0 0                // tpose        [1,N,P,3]
#define O1 491520           // tpose_dirs   [1,N,P,3]
#define O2 983040           // resd         [1,N,P,3]
#define O3 1474560          // pflag        [1,N,P]
#define O4 1638400          // init_bigpose [1,N*P,3]
#define O5 2129920          // pnorm        [1,N*P]

typedef unsigned short ushort_t;
typedef unsigned int   uint_t;
typedef unsigned long long u64_t;
typedef __attribute__((ext_vector_type(8))) short bf16x8;
typedef __attribute__((ext_vector_type(4))) float f32x4;
typedef __attribute__((ext_vector_type(2))) float f32x2;

__device__ __forceinline__ ushort_t f2bf(float f) {
  union { uint_t i; float f; } v; v.f = f;
  uint_t i = v.i;
  return (ushort_t)((i + 0x7FFFu + ((i >> 16) & 1u)) >> 16);  // RNE
}
// hardware packed f32->bf16 (RNE, bit-identical to f2bf for finite values)
__device__ __forceinline__ uint_t cvt_pk_bf16(float lo, float hi) {
  uint_t r;
  asm("v_cvt_pk_bf16_f32 %0, %1, %2" : "=v"(r) : "v"(lo), "v"(hi));
  return r;
}
__device__ __forceinline__ float tanh_fast(float v) {
  v = fminf(fmaxf(v, -15.f), 15.f);
  float e = __expf(2.f*v);               // v_exp_f32 path
  return __fdividef(e - 1.f, e + 1.f);   // abs err < 1e-6, plenty for tolerance
}
// 16-lane sum via DPP row_shl tree (VALU pipe). Result in lane m16==0.
__device__ __forceinline__ float dpp_sum16(float x) {
  x += __int_as_float(__builtin_amdgcn_update_dpp(0, __float_as_int(x), 0x108, 0xF, 0xF, true)); // row_shl:8
  x += __int_as_float(__builtin_amdgcn_update_dpp(0, __float_as_int(x), 0x104, 0xF, 0xF, true)); // row_shl:4
  x += __int_as_float(__builtin_amdgcn_update_dpp(0, __float_as_int(x), 0x102, 0xF, 0xF, true)); // row_shl:2
  x += __int_as_float(__builtin_amdgcn_update_dpp(0, __float_as_int(x), 0x101, 0xF, 0xF, true)); // row_shl:1
  return x;
}

// ---------------- LBS transform for one (n,p) row ----------------
__device__ __forceinline__ void transform_one(
    int n, int p, int nn, float pn, float fl,
    float px, float py, float pz, float dx, float dy, float dz,
    const float* __restrict__ pbw,
    const float4* __restrict__ sA4, const float4* __restrict__ sB4,
    float* __restrict__ out)
{
  const float4* bwr = (const float4*)(pbw + ((size_t)p * MM + nn) * JJ);
  float bw[24];
  #pragma unroll
  for (int q = 0; q < 6; ++q) {
    float4 u = bwr[q];
    bw[q*4+0] = u.x; bw[q*4+1] = u.y; bw[q*4+2] = u.z; bw[q*4+3] = u.w;
  }

  float M1[12], M2[12];
  #pragma unroll
  for (int q = 0; q < 12; ++q) { M1[q] = 0.f; M2[q] = 0.f; }
  #pragma unroll
  for (int j = 0; j < 24; ++j) {
    float w = bw[j];
    float4 a0 = sA4[j*3+0], a1 = sA4[j*3+1], a2 = sA4[j*3+2];
    M1[0]=fmaf(w,a0.x,M1[0]); M1[1]=fmaf(w,a0.y,M1[1]); M1[2]=fmaf(w,a0.z,M1[2]); M1[3]=fmaf(w,a0.w,M1[3]);
    M1[4]=fmaf(w,a1.x,M1[4]); M1[5]=fmaf(w,a1.y,M1[5]); M1[6]=fmaf(w,a1.z,M1[6]); M1[7]=fmaf(w,a1.w,M1[7]);
    M1[8]=fmaf(w,a2.x,M1[8]); M1[9]=fmaf(w,a2.y,M1[9]); M1[10]=fmaf(w,a2.z,M1[10]); M1[11]=fmaf(w,a2.w,M1[11]);
    float4 c0 = sB4[j*3+0], c1 = sB4[j*3+1], c2 = sB4[j*3+2];
    M2[0]=fmaf(w,c0.x,M2[0]); M2[1]=fmaf(w,c0.y,M2[1]); M2[2]=fmaf(w,c0.z,M2[2]); M2[3]=fmaf(w,c0.w,M2[3]);
    M2[4]=fmaf(w,c1.x,M2[4]); M2[5]=fmaf(w,c1.y,M2[5]); M2[6]=fmaf(w,c1.z,M2[6]); M2[7]=fmaf(w,c1.w,M2[7]);
    M2[8]=fmaf(w,c2.x,M2[8]); M2[9]=fmaf(w,c2.y,M2[9]); M2[10]=fmaf(w,c2.z,M2[10]); M2[11]=fmaf(w,c2.w,M2[11]);
  }
  float a=M1[0], b=M1[1], c=M1[2];
  float d=M1[4], e=M1[5], f=M1[6];
  float g=M1[8], h=M1[9], i=M1[10];
  float C00 = e*i - f*h, C01 = c*h - b*i, C02 = b*f - c*e;
  float C10 = f*g - d*i, C11 = a*i - c*g, C12 = c*d - a*f;
  float C20 = d*h - e*g, C21 = b*g - a*h, C22 = a*e - b*d;
  float det = a*C00 + b*C10 + c*C20;
  float rd = 1.0f / det;
  float tx = px - M1[3], ty = py - M1[7], tz = pz - M1[11];
  float t0 = rd * (C00*tx + C01*ty + C02*tz);
  float t1 = rd * (C10*tx + C11*ty + C12*tz);
  float t2 = rd * (C20*tx + C21*ty + C22*tz);
  float i0 = M2[0]*t0 + M2[1]*t1 + M2[2]*t2  + M2[3];
  float i1 = M2[4]*t0 + M2[5]*t1 + M2[6]*t2  + M2[7];
  float i2 = M2[8]*t0 + M2[9]*t1 + M2[10]*t2 + M2[11];
  float d0 = rd * (C00*dx + C01*dy + C02*dz);
  float d1 = rd * (C10*dx + C11*dy + C12*dz);
  float d2 = rd * (C20*dx + C21*dy + C22*dz);
  float e0 = M2[0]*d0 + M2[1]*d1 + M2[2]*d2;
  float e1 = M2[4]*d0 + M2[5]*d1 + M2[6]*d2;
  float e2 = M2[8]*d0 + M2[9]*d1 + M2[10]*d2;

  size_t k = (size_t)n * PP + p;   // n-major
  out[O1 + k*3+0] = e0; out[O1 + k*3+1] = e1; out[O1 + k*3+2] = e2;
  out[O3 + k] = fl;
  out[O4 + k*3+0] = i0; out[O4 + k*3+1] = i1; out[O4 + k*3+2] = i2;
  out[O5 + k] = pn;
}

// grid: 1536 blocks x 256 threads. Blocks >=1280 do the W2->bf16 prep.
// (round-13 verified nn: block-min scan + deterministic replay argmin.)
__global__ __launch_bounds__(256) void nn_kernel(
    const float* __restrict__ pp0, const float* __restrict__ pp1,
    const float* __restrict__ part_pts, const float* __restrict__ pbw,
    const float* __restrict__ Ag, const float* __restrict__ Bg,
    const int* __restrict__ lengths2,
    const float* __restrict__ W2g, ushort_t* __restrict__ W2bf,
    float* __restrict__ out)
{
  // folded W2 prep (former prep_w2): blocks 1280..1535, k = bid-1280
  if (blockIdx.x >= 1280) {
    int k = blockIdx.x - 1280;
    int n = threadIdx.x;
    float v = W2g[k*256 + n];
    int kc = k >> 5, quad = (k & 31) >> 3, j = k & 7;
    int tile = n >> 4, lane = quad*16 + (n & 15);
    W2bf[kc*8192 + tile*512 + lane*8 + j] = f2bf(v);
    return;
  }

  __shared__ float4 sXq[256], sYq[256], sZq[256], sWq[256];  // SoA quads
  __shared__ float4 sA4[72];
  __shared__ float4 sB4[72];
  int t = threadIdx.x;
  int p  = blockIdx.x >> 8;        // 256 blocks per part
  int nb = blockIdx.x & 255;
  int g  = t >> 3;                 // n-group 0..31
  int s  = t & 7;                  // m-slice 0..7
  int n0 = nb*128 + g*4;           // this lane's 4 points: n0..n0+3

  // pose-pair disambiguation (wave-uniform); pose_dirs rows unit-norm
  float s0r0 = pp0[0], s0r1 = pp0[1], s0r2 = pp0[2];
  float nrm = s0r0*s0r0 + s0r1*s0r1 + s0r2*s0r2;
  bool c0_is_dirs = fabsf(nrm - 1.0f) < 1e-4f;
  const float* pose_pts  = c0_is_dirs ? pp1 : pp0;
  const float* pose_dirs = c0_is_dirs ? pp0 : pp1;

  {
    #pragma clang fp contract(off)
    float* fX = (float*)sXq; float* fY = (float*)sYq;
    float* fZ = (float*)sZq; float* fW = (float*)sWq;
    for (int i = t; i < MM; i += 256) {
      float x = part_pts[((size_t)p*MM+i)*3+0];
      float y = part_pts[((size_t)p*MM+i)*3+1];
      float z = part_pts[((size_t)p*MM+i)*3+2];
      float yy = ((x*x) + (y*y)) + (z*z);
      fX[i] = x; fY[i] = y; fZ[i] = z; fW[i] = yy;
    }
  }
  for (int i = t; i < 72; i += 256) {
    int l = i*4;
    int j = l / 12, rc = l % 12;
    float4 qa, qb;
    qa.x = Ag[j*16+rc+0]; qa.y = Ag[j*16+rc+1]; qa.z = Ag[j*16+rc+2]; qa.w = Ag[j*16+rc+3];
    qb.x = Bg[j*16+rc+0]; qb.y = Bg[j*16+rc+1]; qb.z = Bg[j*16+rc+2]; qb.w = Bg[j*16+rc+3];
    sA4[i] = qa; sB4[i] = qb;
  }
  int mlen = lengths2[p]; if (mlen > MM) mlen = MM;
  __syncthreads();

  // load 4 points' coordinates (n0 % 4 == 0 -> 16B aligned); build doubled splats
  float X[4], Y[4], Z[4];
  f32x2 Xd[4], Yd[4], Zd[4], C2[4];
  {
    #pragma clang fp contract(off)
    const float4* pr = (const float4*)(pose_pts + (size_t)n0*3);
    float4 f0 = pr[0], f1 = pr[1], f2 = pr[2];
    X[0]=f0.x; Y[0]=f0.y; Z[0]=f0.z;
    X[1]=f0.w; Y[1]=f1.x; Z[1]=f1.y;
    X[2]=f1.z; Y[2]=f1.w; Z[2]=f2.x;
    X[3]=f2.y; Y[3]=f2.z; Z[3]=f2.w;
    #pragma unroll
    for (int j = 0; j < 4; ++j) {
      float x2 = ((X[j]*X[j]) + (Y[j]*Y[j])) + (Z[j]*Z[j]);
      Xd[j] = (f32x2){2.0f*X[j], 2.0f*X[j]};
      Yd[j] = (f32x2){2.0f*Y[j], 2.0f*Y[j]};
      Zd[j] = (f32x2){2.0f*Z[j], 2.0f*Z[j]};
      C2[j] = (f32x2){x2, x2};
    }
  }

  float best[4]  = {INFINITY, INFINITY, INFINITY, INFINITY};
  int   kb[4]    = {0, 0, 0, 0};   // winning 32-block id (main scan)
  int   mbest[4] = {0, 0, 0, 0};   // final m index
  int   nq = mlen >> 5;            // full 32-blocks
  {
    #pragma clang fp contract(off)
    for (int k = 0; k < nq; ++k) {
      int qi = k*8 + s;                // quad index (8-way same-addr broadcast)
      float4 QX = sXq[qi], QY = sYq[qi], QZ = sZq[qi], QW = sWq[qi];
      f32x2 qx0 = {QX.x, QX.y}, qx1 = {QX.z, QX.w};
      f32x2 qy0 = {QY.x, QY.y}, qy1 = {QY.z, QY.w};
      f32x2 qz0 = {QZ.x, QZ.y}, qz1 = {QZ.z, QZ.w};
      f32x2 qw0 = {QW.x, QW.y}, qw1 = {QW.z, QW.w};
      #pragma unroll
      for (int j = 0; j < 4; ++j) {
        f32x2 dt0 = ((Xd[j]*qx0) + (Yd[j]*qy0)) + (Zd[j]*qz0);
        f32x2 tt0 = (C2[j] - dt0) + qw0;
        f32x2 dt1 = ((Xd[j]*qx1) + (Yd[j]*qy1)) + (Zd[j]*qz1);
        f32x2 tt1 = (C2[j] - dt1) + qw1;
        float e0 = fmaxf(tt0.x, 0.f);
        float e1 = fmaxf(tt0.y, 0.f);
        float e2 = fmaxf(tt1.x, 0.f);
        float e3 = fmaxf(tt1.y, 0.f);
        float m01 = fminf(e0, e1);
        float m23 = fminf(e2, e3);
        float lmin = fminf(m01, m23);
        bool lt = lmin < best[j];            // strict: first block keeps win
        best[j] = fminf(best[j], lmin);
        kb[j] = lt ? k : kb[j];
      }
    }
    // deterministic replay of the winning block -> exact first-min index
    if (nq > 0) {
      #pragma unroll
      for (int j = 0; j < 4; ++j) {
        int qi = kb[j]*8 + s;
        float4 QX = sXq[qi], QY = sYq[qi], QZ = sZq[qi], QW = sWq[qi];
        float dA = ((Xd[j].x*QX.x) + (Yd[j].x*QY.x)) + (Zd[j].x*QZ.x);
        float eA = fmaxf((C2[j].x - dA) + QW.x, 0.f);
        float dB = ((Xd[j].x*QX.y) + (Yd[j].x*QY.y)) + (Zd[j].x*QZ.y);
        float eB = fmaxf((C2[j].x - dB) + QW.y, 0.f);
        float dC = ((Xd[j].x*QX.z) + (Yd[j].x*QY.z)) + (Zd[j].x*QZ.z);
        float eC = fmaxf((C2[j].x - dC) + QW.z, 0.f);
        // first element equal to best (eD implied if others miss)
        int e = (eA == best[j]) ? 0 : (eB == best[j]) ? 1 : (eC == best[j]) ? 2 : 3;
        mbest[j] = (kb[j] << 5) + 4*s + e;
      }
    } else {
      #pragma unroll
      for (int j = 0; j < 4; ++j) mbest[j] = 4*s;
    }
    // tail: partial 32-block (not taken when mlen % 32 == 0)
    int mb0 = nq << 5;
    if (mb0 < mlen) {
      const float* fX = (const float*)sXq; const float* fY = (const float*)sYq;
      const float* fZ = (const float*)sZq; const float* fW = (const float*)sWq;
      #pragma unroll
      for (int e = 0; e < 4; ++e) {
        int m = mb0 + 4*s + e;
        if (m < mlen) {
          float qx = fX[m], qy = fY[m], qz = fZ[m], qw = fW[m];
          #pragma unroll
          for (int j = 0; j < 4; ++j) {
            float dt2 = ((Xd[j].x*qx) + (Yd[j].x*qy)) + (Zd[j].x*qz);
            float dd = fmaxf((C2[j].x - dt2) + qw, 0.0f);
            bool lt = dd < best[j];          // strict: earlier m wins ties
            best[j] = fminf(best[j], dd);
            mbest[j] = lt ? m : mbest[j];
          }
        }
      }
    }
  }

  // merge the 8 slices (butterfly within each 8-lane group), lexicographic
  u64_t pk[4];
  #pragma unroll
  for (int j = 0; j < 4; ++j) {
    pk[j] = ((u64_t)__float_as_uint(best[j]) << 32) | (uint_t)mbest[j];
    u64_t o;
    o = __shfl_xor(pk[j], 1); if (o < pk[j]) pk[j] = o;
    o = __shfl_xor(pk[j], 2); if (o < pk[j]) pk[j] = o;
    o = __shfl_xor(pk[j], 4); if (o < pk[j]) pk[j] = o;
  }

  // lanes s=0..3 each transform one point (no redistribution shuffles)
  if (s < 4) {
    u64_t mypk = (s==0) ? pk[0] : (s==1) ? pk[1] : (s==2) ? pk[2] : pk[3];
    float xa = (s==0) ? X[0] : (s==1) ? X[1] : (s==2) ? X[2] : X[3];
    float ya = (s==0) ? Y[0] : (s==1) ? Y[1] : (s==2) ? Y[2] : Y[3];
    float za = (s==0) ? Z[0] : (s==1) ? Z[1] : (s==2) ? Z[2] : Z[3];
    int n = n0 + s;
    int bm = (int)(mypk & 0xFFFFFFFFull);
    float bd = __uint_as_float((uint_t)(mypk >> 32));
    float pn = sqrtf(bd);
    float fl = ((double)pn < 0.08) ? 1.0f : 0.0f;
    float dxa = pose_dirs[n*3+0], dya = pose_dirs[n*3+1], dza = pose_dirs[n*3+2];
    transform_one(n, p, bm, pn, fl, xa, ya, za, dxa, dya, dza, pbw, sA4, sB4, out);
  }
}

// ---------------- MLP: r10 structure + conflict-free build ----------------
// grid: 2560 blocks x 256 threads (4 waves); block = 64 rows x 256 cols,
// single pass (r10 structure: B read once per block = 327MB L2 total).
// Round-13 diagnosis: the sH build's thread->(col-octet, row-group) mapping
// put all 64 lanes of each ds_write_b128 in ONE 4-bank group (byte%128 =
// 16*(r15%8), r15%8 fixed per store) -> 9.17M bank conflicts (~15us).
// Fix: thread t owns ROW r = t&63 and iterates its wave's 8 col-octets;
// now r15 = lane&15 varies per lane -> byte%128 spans all bank groups ->
// minimum-cycle writes. h1 exprs / cvt_pk pairing / sH logical layout
// (entry = qd*16+r15) / K-loop / epilogue are r10-verbatim -> h2
// bit-identical; layer-3 association identical to r10/r13 (passed at
// absmax 0.0039 vs 0.0447 threshold).
__global__ __launch_bounds__(256) void mlp_kernel(
    const float* __restrict__ W1g, const float* __restrict__ b1g,
    const float* __restrict__ b2g, const float* __restrict__ W3g,
    const float* __restrict__ b3g, const ushort_t* __restrict__ W2bf,
    float* __restrict__ out)
{
  __shared__ ushort_t sH[4*8*512];   // 32KB: h1 A-frags [mt][kc][qd*16+r15][8]
  __shared__ float4 w1c[256];        // {W1[0][c], W1[1][c], W1[2][c], b1[c]}
  __shared__ float4 w3b2[256];       // {W3[c][0], W3[c][1], W3[c][2], b2[c]}
  __shared__ float4 sRow[64];        // {x, y, z, pflag} per row
  __shared__ float  prt[64][4][3];   // per-row layer-3 partials per wave

  int t = threadIdx.x;
  int wave = t >> 6, lane = t & 63, quad = lane >> 4, m16 = lane & 15;
  size_t row0 = (size_t)blockIdx.x * 64;

  {
    int c = t;   // 256 threads exactly
    w1c[c]  = make_float4(W1g[c], W1g[256+c], W1g[512+c], b1g[c]);
    w3b2[c] = make_float4(W3g[c*3+0], W3g[c*3+1], W3g[c*3+2], b2g[c]);
    if (t < 64) {
      size_t r = row0 + t;
      sRow[t] = make_float4(out[O4 + r*3+0], out[O4 + r*3+1], out[O4 + r*3+2],
                            out[O3 + r]);
    }
  }
  __syncthreads();

  // build sH: thread t -> row r = t&63; octets o = (t>>6)*8 + j (j=0..7).
  // Store lanes vary r15 -> bank-spread writes. w1c reads are wave-uniform
  // broadcasts (o same across the wave's lanes).
  {
    int r = t & 63;
    float4 xyz = sRow[r];
    int mt = r >> 4, r15 = r & 15;
    #pragma unroll
    for (int j = 0; j < 8; ++j) {
      int o = wave*8 + j;
      int kcw = o >> 2, qd = o & 3;
      int c0 = kcw*32 + qd*8;
      uint_t u0, u1, u2, u3;
      {
        float4 wA = w1c[c0 + 0], wB = w1c[c0 + 1];
        float hA = fmaxf(fmaf(xyz.z, wA.z, fmaf(xyz.y, wA.y, fmaf(xyz.x, wA.x, wA.w))), 0.f);
        float hB = fmaxf(fmaf(xyz.z, wB.z, fmaf(xyz.y, wB.y, fmaf(xyz.x, wB.x, wB.w))), 0.f);
        u0 = cvt_pk_bf16(hA, hB);
      }
      {
        float4 wA = w1c[c0 + 2], wB = w1c[c0 + 3];
        float hA = fmaxf(fmaf(xyz.z, wA.z, fmaf(xyz.y, wA.y, fmaf(xyz.x, wA.x, wA.w))), 0.f);
        float hB = fmaxf(fmaf(xyz.z, wB.z, fmaf(xyz.y, wB.y, fmaf(xyz.x, wB.x, wB.w))), 0.f);
        u1 = cvt_pk_bf16(hA, hB);
      }
      {
        float4 wA = w1c[c0 + 4], wB = w1c[c0 + 5];
        float hA = fmaxf(fmaf(xyz.z, wA.z, fmaf(xyz.y, wA.y, fmaf(xyz.x, wA.x, wA.w))), 0.f);
        float hB = fmaxf(fmaf(xyz.z, wB.z, fmaf(xyz.y, wB.y, fmaf(xyz.x, wB.x, wB.w))), 0.f);
        u2 = cvt_pk_bf16(hA, hB);
      }
      {
        float4 wA = w1c[c0 + 6], wB = w1c[c0 + 7];
        float hA = fmaxf(fmaf(xyz.z, wA.z, fmaf(xyz.y, wA.y, fmaf(xyz.x, wA.x, wA.w))), 0.f);
        float hB = fmaxf(fmaf(xyz.z, wB.z, fmaf(xyz.y, wB.y, fmaf(xyz.x, wB.x, wB.w))), 0.f);
        u3 = cvt_pk_bf16(hA, hB);
      }
      *(uint4*)(&sH[((mt*8 + kcw)*64 + qd*16 + r15)*8]) = make_uint4(u0, u1, u2, u3);
    }
  }
  __syncthreads();

  // K-loop: wave owns cols nt in [wave*4, wave*4+4)
  const ushort_t* Wlane = W2bf + (size_t)wave*2048 + lane*8;
  bf16x8 Bcur[4], Bnxt[4];
  #pragma unroll
  for (int q = 0; q < 4; ++q) Bcur[q] = *(const bf16x8*)(Wlane + q*512);  // kc=0

  f32x4 acc[16];                   // acc[mt*4+q]
  #pragma unroll
  for (int i = 0; i < 16; ++i) acc[i] = (f32x4){0.f,0.f,0.f,0.f};

  #pragma unroll 1
  for (int kc = 0; kc < 8; ++kc) {
    bf16x8 Af[4];
    #pragma unroll
    for (int mt = 0; mt < 4; ++mt)
      Af[mt] = *(const bf16x8*)(&sH[((mt*8 + kc)*64 + lane)*8]);
    if (kc < 7) {                  // prefetch next kc's B under this kc's MFMAs
      #pragma unroll
      for (int q = 0; q < 4; ++q)
        Bnxt[q] = *(const bf16x8*)(Wlane + (kc+1)*8192 + q*512);
    }
    #pragma unroll
    for (int mt = 0; mt < 4; ++mt)
      #pragma unroll
      for (int q = 0; q < 4; ++q)
        acc[mt*4+q] = __builtin_amdgcn_mfma_f32_16x16x32_bf16(Af[mt], Bcur[q], acc[mt*4+q], 0, 0, 0);
    if (kc < 7) {
      #pragma unroll
      for (int q = 0; q < 4; ++q) Bcur[q] = Bnxt[q];
    }
  }

  // epilogue: h2[row=mt*16+quad*4+reg][col=(wave*4+q)*16+m16] = acc[mt*4+q][reg]
  float4 cvq[4];
  #pragma unroll
  for (int q = 0; q < 4; ++q) cvq[q] = w3b2[(wave*4+q)*16 + m16];

  #pragma unroll
  for (int mt = 0; mt < 4; ++mt) {
    #pragma unroll
    for (int reg = 0; reg < 4; ++reg) {
      float q0 = 0.f, q1 = 0.f, q2 = 0.f;
      #pragma unroll
      for (int q = 0; q < 4; ++q) {
        float h2 = fmaxf(acc[mt*4+q][reg] + cvq[q].w, 0.f);
        q0 = fmaf(h2, cvq[q].x, q0);
        q1 = fmaf(h2, cvq[q].y, q1);
        q2 = fmaf(h2, cvq[q].z, q2);
      }
      q0 = dpp_sum16(q0);
      q1 = dpp_sum16(q1);
      q2 = dpp_sum16(q2);
      if (m16 == 0) {
        int lr = mt*16 + quad*4 + reg;           // local row 0..63
        prt[lr][wave][0] = q0;
        prt[lr][wave][1] = q1;
        prt[lr][wave][2] = q2;
      }
    }
  }
  __syncthreads();

  // combine: thread t -> (row = t>>2, comp = t&3), comp<3 active
  {
    int lr = t >> 2, c = t & 3;
    if (c < 3) {
      float v = ((prt[lr][0][c] + prt[lr][1][c]) + prt[lr][2][c]) + prt[lr][3][c];
      size_t r = row0 + lr;
      float4 ib = sRow[lr];
      float iv = (c == 0) ? ib.x : (c == 1) ? ib.y : ib.z;
      float rr = 0.05f * tanh_fast(v + b3g[c]) * ib.w;
      out[O0 + r*3 + c] = iv + rr;
      out[O2 + r*3 + c] = rr;
    }
  }
}

extern "C" void kernel_launch(void* const* d_in, const int* in_sizes, int n_in,
                              void* d_out, int out_size, void* d_ws, size_t ws_size,
                              hipStream_t stream) {
  (void)out_size; (void)ws_size;
  // size-based slot remap (no-op under documented dict order; protective otherwise)
  const int want[13] = {98304, 98304, 15360, 122880, 384, 384, 768, 256, 65536, 256, 768, 3, 5};
  int idx[13];
  bool used[64] = {false};
  for (int L = 0; L < 13; ++L) {
    idx[L] = -1;
    for (int s = 0; s < n_in && s < 64; ++s) {
      if (!used[s] && in_sizes[s] == want[L]) { idx[L] = s; used[s] = true; break; }
    }
    if (idx[L] < 0) idx[L] = L;
  }
  const float* pp0       = (const float*)d_in[idx[0]];
  const float* pp1       = (const float*)d_in[idx[1]];
  const float* part_pts  = (const float*)d_in[idx[2]];
  const float* part_pbw  = (const float*)d_in[idx[3]];
  const float* A         = (const float*)d_in[idx[4]];
  const float* bigA      = (const float*)d_in[idx[5]];
  const float* W1        = (const float*)d_in[idx[6]];
  const float* b1        = (const float*)d_in[idx[7]];
  const float* W2        = (const float*)d_in[idx[8]];
  const float* b2        = (const float*)d_in[idx[9]];
  const float* W3        = (const float*)d_in[idx[10]];
  const float* b3        = (const float*)d_in[idx[11]];
  const int*   lengths2  = (const int*)d_in[idx[12]];
  float* out = (float*)d_out;
  ushort_t* W2bf = (ushort_t*)d_ws;   // 128 KB of workspace

  nn_kernel<<<1536, 256, 0, stream>>>(pp0, pp1, part_pts, part_pbw,
                                      A, bigA, lengths2, W2, W2bf, out);
  mlp_kernel<<<2560, 256, 0, stream>>>(W1, b1, b2, W3, b3, W2bf, out);
}